// Round 7
// baseline (234.384 us; speedup 1.0000x reference)
//
#include <hip/hip_runtime.h>
#include <hip/hip_bf16.h>

typedef __bf16 bf16x8 __attribute__((ext_vector_type(8)));
typedef float f32x4 __attribute__((ext_vector_type(4)));
typedef unsigned short ushort_t;
typedef ushort_t ushort8 __attribute__((ext_vector_type(8)));
typedef unsigned uint2v __attribute__((ext_vector_type(2)));
typedef unsigned uint4v __attribute__((ext_vector_type(4)));

#define DIM 512
#define HEADS 8
#define HD 64
#define HWN 4096   // 64*64 queries per batch
#define KVN 1024   // 32*32 kv tokens per batch
#define KKV 2048   // 512*2*2 im2col K for the strided conv
#define LOG2E 1.44269504f

__device__ __forceinline__ ushort_t f2bf(float f) {
    union { float f; unsigned u; } v; v.f = f;
    unsigned r = v.u + 0x7fffu + ((v.u >> 16) & 1u);
    return (ushort_t)(r >> 16);
}

// pack two f32 -> one dword of 2 bf16 (RNE), low16 = lo
__device__ __forceinline__ unsigned cvtpk(float lo, float hi) {
    unsigned r;
    asm("v_cvt_pk_bf16_f32 %0, %1, %2" : "=v"(r) : "v"(lo), "v"(hi));
    return r;
}

__device__ __forceinline__ void pl32swap(unsigned &a, unsigned &b) {
    asm("v_permlane32_swap_b32 %0, %1" : "+v"(a), "+v"(b));
}
__device__ __forceinline__ void pl16swap(unsigned &a, unsigned &b) {
    asm("v_permlane16_swap_b32 %0, %1" : "+v"(a), "+v"(b));
}

__device__ __forceinline__ bf16x8 frag4(unsigned a, unsigned b, unsigned c, unsigned d) {
    uint4v t; t[0] = a; t[1] = b; t[2] = c; t[3] = d;
    return __builtin_bit_cast(bf16x8, t);
}

// async global->LDS, 16 B per lane; lds dest is wave-uniform base + lane*16
__device__ __forceinline__ void gload_lds16(const ushort_t* g, ushort_t* l) {
    __builtin_amdgcn_global_load_lds(
        (const __attribute__((address_space(1))) unsigned int*)(const void*)g,
        (__attribute__((address_space(3))) unsigned int*)(void*)l,
        16, 0, 0);
}

// explicit drain of outstanding global_load_lds before the barrier
__device__ __forceinline__ void drain_sync() {
    asm volatile("s_waitcnt vmcnt(0)" ::: "memory");
    __syncthreads();
}

// ---------------------------------------------------------------------------
// Kernel 0a: small f32 -> bf16 convert (wq, wout)
// ---------------------------------------------------------------------------
__global__ __launch_bounds__(256) void cvt_kernel(
        const float* __restrict__ src, ushort_t* __restrict__ dst, int n8) {
    int i = blockIdx.x * 256 + threadIdx.x;
    if (i >= n8) return;
    const float* p = &src[(size_t)i * 8];
    f32x4 v0 = *(const f32x4*)&p[0];
    f32x4 v1 = *(const f32x4*)&p[4];
    ushort8 w;
    w[0] = f2bf(v0[0]); w[1] = f2bf(v0[1]); w[2] = f2bf(v0[2]); w[3] = f2bf(v0[3]);
    w[4] = f2bf(v1[0]); w[5] = f2bf(v1[1]); w[6] = f2bf(v1[2]); w[7] = f2bf(v1[3]);
    *(ushort8*)&dst[i * 8] = w;
}

// ---------------------------------------------------------------------------
// Kernel 0b: x f32 [b][c][p] -> xT bf16 [b][p][c]   (tiled 64x64 transpose)
// ---------------------------------------------------------------------------
__global__ __launch_bounds__(256) void cvt_xT_kernel(
        const float* __restrict__ x, ushort_t* __restrict__ xT) {
    const int b  = blockIdx.z;
    const int c0 = blockIdx.y * 64;
    const int p0 = blockIdx.x * 64;
    __shared__ ushort_t tile[64 * 72];

    const int tid = threadIdx.x;
    {
        int r = tid >> 2, pc = (tid & 3) * 16;
        const float* src = &x[((size_t)b * DIM + c0 + r) * HWN + p0 + pc];
        f32x4 v0 = *(const f32x4*)&src[0];
        f32x4 v1 = *(const f32x4*)&src[4];
        f32x4 v2 = *(const f32x4*)&src[8];
        f32x4 v3 = *(const f32x4*)&src[12];
        ushort8 w0, w1;
        w0[0]=f2bf(v0[0]); w0[1]=f2bf(v0[1]); w0[2]=f2bf(v0[2]); w0[3]=f2bf(v0[3]);
        w0[4]=f2bf(v1[0]); w0[5]=f2bf(v1[1]); w0[6]=f2bf(v1[2]); w0[7]=f2bf(v1[3]);
        w1[0]=f2bf(v2[0]); w1[1]=f2bf(v2[1]); w1[2]=f2bf(v2[2]); w1[3]=f2bf(v2[3]);
        w1[4]=f2bf(v3[0]); w1[5]=f2bf(v3[1]); w1[6]=f2bf(v3[2]); w1[7]=f2bf(v3[3]);
        *(ushort8*)&tile[r * 72 + pc]     = w0;
        *(ushort8*)&tile[r * 72 + pc + 8] = w1;
    }
    __syncthreads();
    {
        int p = tid >> 2, cc = (tid & 3) * 16;
        ushort8 w0, w1;
        #pragma unroll
        for (int j = 0; j < 8; ++j) {
            w0[j] = tile[(cc + j) * 72 + p];
            w1[j] = tile[(cc + 8 + j) * 72 + p];
        }
        ushort_t* dst = &xT[((size_t)b * HWN + p0 + p) * DIM + c0 + cc];
        *(ushort8*)&dst[0] = w0;
        *(ushort8*)&dst[8] = w1;
    }
}

// ---------------------------------------------------------------------------
// Kernel 0c: wkv f32 [o2][c][di][dj] -> wkvT bf16 [o2][(di*2+dj)*512 + c]
// ---------------------------------------------------------------------------
__global__ __launch_bounds__(256) void cvt_wkvT_kernel(
        const float* __restrict__ wkv, ushort_t* __restrict__ wkvT) {
    int i = blockIdx.x * 256 + threadIdx.x;
    if (i >= 1024 * 512) return;
    int o2 = i >> 9, c = i & 511;
    f32x4 v = *(const f32x4*)&wkv[(size_t)i * 4];
    #pragma unroll
    for (int q = 0; q < 4; ++q)
        wkvT[(size_t)o2 * KKV + q * 512 + c] = f2bf(v[q]);
}

// ---------------------------------------------------------------------------
// Shared GEMM machinery: 128x128 tile, BK=64, double-buffered prefetch,
// LINEAR LDS [128 rows][64 k-elems].
// ---------------------------------------------------------------------------
__device__ __forceinline__ void gemm_compute64(
        const ushort_t* __restrict__ sA, const ushort_t* __restrict__ sB,
        int wm, int wn, int l15, int quad, f32x4 (&acc)[4][4]) {
    bf16x8 a[2][4], bb[2][4];
    #pragma unroll
    for (int kk = 0; kk < 2; ++kk)
        #pragma unroll
        for (int i = 0; i < 4; ++i) {
            a[kk][i]  = *(const bf16x8*)&sA[(wm + i * 16 + l15) * 64 + (kk * 4 + quad) * 8];
            bb[kk][i] = *(const bf16x8*)&sB[(wn + i * 16 + l15) * 64 + (kk * 4 + quad) * 8];
        }
    #pragma unroll
    for (int i = 0; i < 4; ++i)
        #pragma unroll
        for (int j = 0; j < 4; ++j) {
            acc[i][j] = __builtin_amdgcn_mfma_f32_16x16x32_bf16(a[0][i], bb[0][j], acc[i][j], 0, 0, 0);
            acc[i][j] = __builtin_amdgcn_mfma_f32_16x16x32_bf16(a[1][i], bb[1][j], acc[i][j], 0, 0, 0);
        }
}

// ---------------------------------------------------------------------------
// Kernel 1: Q projection.  Qs[b][o][p] = (0.125*log2e) * sum_c Wq[o][c]*X[c][p]
// ---------------------------------------------------------------------------
__global__ __launch_bounds__(256) void qproj_kernel(
        const ushort_t* __restrict__ xT, const ushort_t* __restrict__ wqb,
        ushort_t* __restrict__ qs) {
    const int b  = blockIdx.z;
    const int m0 = blockIdx.y * 128;
    const int n0 = blockIdx.x * 128;

    __shared__ ushort_t shA[2][128 * 64];
    __shared__ ushort_t shB[2][128 * 64];

    const int tid  = threadIdx.x;
    const int wave = tid >> 6;
    const int lane = tid & 63;
    const int l15  = lane & 15;
    const int quad = lane >> 4;
    const int wm   = (wave >> 1) * 64;
    const int wn   = (wave & 1) * 64;
    const int r8   = lane >> 3;          // row within 8-row group
    const int c8   = lane & 7;           // linear 16B chunk

    const ushort_t* aS[4];
    const ushort_t* bS[4];
    #pragma unroll
    for (int g = 0; g < 4; ++g) {
        int row = wave * 32 + g * 8 + r8;
        aS[g] = &wqb[(size_t)(m0 + row) * DIM + c8 * 8];
        bS[g] = &xT[((size_t)b * HWN + n0 + row) * DIM + c8 * 8];
    }
    const int ldso = wave * 32 * 64;

    f32x4 zero = {0.f, 0.f, 0.f, 0.f};
    f32x4 acc[4][4];
    #pragma unroll
    for (int i = 0; i < 4; ++i)
        #pragma unroll
        for (int j = 0; j < 4; ++j) acc[i][j] = zero;

    #pragma unroll
    for (int g = 0; g < 4; ++g) {
        gload_lds16(aS[g], &shA[0][ldso + g * 512]);
        gload_lds16(bS[g], &shB[0][ldso + g * 512]);
    }
    drain_sync();

    for (int t = 0; t < 8; ++t) {
        const int cur = t & 1;
        if (t < 7) {
            const int ko = (t + 1) * 64;
            #pragma unroll
            for (int g = 0; g < 4; ++g) {
                gload_lds16(aS[g] + ko, &shA[cur ^ 1][ldso + g * 512]);
                gload_lds16(bS[g] + ko, &shB[cur ^ 1][ldso + g * 512]);
            }
        }
        gemm_compute64(shA[cur], shB[cur], wm, wn, l15, quad, acc);
        drain_sync();
    }

    #pragma unroll
    for (int i = 0; i < 4; ++i)
        #pragma unroll
        for (int j = 0; j < 4; ++j)
            #pragma unroll
            for (int r = 0; r < 4; ++r) {
                int m = m0 + wm + i * 16 + quad * 4 + r;
                int n = n0 + wn + j * 16 + l15;
                qs[((size_t)b * DIM + m) * HWN + n] =
                    f2bf(acc[i][j][r] * (0.125f * LOG2E));
            }
}

// ---------------------------------------------------------------------------
// Kernel 2: KV conv-GEMM.  A = wkvT [1024][2048], B = im2col-gathered xT.
// ---------------------------------------------------------------------------
__global__ __launch_bounds__(256) void kv_kernel(
        const ushort_t* __restrict__ xT, const ushort_t* __restrict__ wkvT,
        ushort_t* __restrict__ ks, ushort_t* __restrict__ vt) {
    const int b  = blockIdx.z;
    const int m0 = blockIdx.y * 128;
    const int j0 = blockIdx.x * 128;

    __shared__ ushort_t shA[2][128 * 64];
    __shared__ ushort_t shB[2][128 * 64];

    const int tid  = threadIdx.x;
    const int wave = tid >> 6;
    const int lane = tid & 63;
    const int l15  = lane & 15;
    const int quad = lane >> 4;
    const int wm   = (wave >> 1) * 64;
    const int wn   = (wave & 1) * 64;
    const int r8   = lane >> 3;
    const int c8   = lane & 7;

    const ushort_t* aS[4];
    const ushort_t* bS[4];
    #pragma unroll
    for (int g = 0; g < 4; ++g) {
        int row = wave * 32 + g * 8 + r8;
        aS[g] = &wkvT[(size_t)(m0 + row) * KKV + c8 * 8];
        int jr = j0 + row;
        int y = jr >> 5, x = jr & 31;
        bS[g] = &xT[((size_t)b * HWN + 128 * y + 2 * x) * DIM + c8 * 8];
    }
    const int ldso = wave * 32 * 64;

    f32x4 zero = {0.f, 0.f, 0.f, 0.f};
    f32x4 acc[4][4];
    #pragma unroll
    for (int i = 0; i < 4; ++i)
        #pragma unroll
        for (int j = 0; j < 4; ++j) acc[i][j] = zero;

    // step t covers k' = t*64..t*64+63:  q = t>>3, kc = (t&7)*64
    #pragma unroll
    for (int g = 0; g < 4; ++g) {
        gload_lds16(aS[g], &shA[0][ldso + g * 512]);
        gload_lds16(bS[g], &shB[0][ldso + g * 512]);
    }
    drain_sync();

    for (int t = 0; t < 32; ++t) {
        const int cur = t & 1;
        if (t < 31) {
            const int tn = t + 1;
            const int qn = tn >> 3;
            const int ao = tn * 64;
            const int bo = (64 * (qn >> 1) + (qn & 1)) * DIM + (tn & 7) * 64;
            #pragma unroll
            for (int g = 0; g < 4; ++g) {
                gload_lds16(aS[g] + ao, &shA[cur ^ 1][ldso + g * 512]);
                gload_lds16(bS[g] + bo, &shB[cur ^ 1][ldso + g * 512]);
            }
        }
        gemm_compute64(shA[cur], shB[cur], wm, wn, l15, quad, acc);
        drain_sync();
    }

    if (m0 < DIM) {
        // K half: tile spans heads h0, h0+1.  Transpose passes through shA.
        ushort_t* cbuf = &shA[0][0];
        const int h0 = m0 >> 6;
        #pragma unroll
        for (int mh = 0; mh < 2; ++mh) {
            if ((wave >> 1) == mh) {
                #pragma unroll
                for (int i = 0; i < 4; ++i)
                    #pragma unroll
                    for (int j = 0; j < 4; ++j)
                        #pragma unroll
                        for (int r = 0; r < 4; ++r) {
                            int mloc = i * 16 + quad * 4 + r;      // 0..63 (= d)
                            int n    = wn + j * 16 + l15;          // 0..127
                            cbuf[n * 72 + mloc] = f2bf(acc[i][j][r]);
                        }
            }
            __syncthreads();
            {
                int n = tid >> 1, doff = (tid & 1) * 32;
                ushort8 u0 = *(const ushort8*)&cbuf[n * 72 + doff];
                ushort8 u1 = *(const ushort8*)&cbuf[n * 72 + doff + 8];
                ushort8 u2 = *(const ushort8*)&cbuf[n * 72 + doff + 16];
                ushort8 u3 = *(const ushort8*)&cbuf[n * 72 + doff + 24];
                ushort_t* dst =
                    &ks[(((size_t)b * HEADS + h0 + mh) * KVN + j0 + n) * HD + doff];
                *(ushort8*)&dst[0]  = u0;
                *(ushort8*)&dst[8]  = u1;
                *(ushort8*)&dst[16] = u2;
                *(ushort8*)&dst[24] = u3;
            }
            __syncthreads();
        }
    } else {
        #pragma unroll
        for (int i = 0; i < 4; ++i)
            #pragma unroll
            for (int j = 0; j < 4; ++j)
                #pragma unroll
                for (int r = 0; r < 4; ++r) {
                    int mfull = m0 - DIM + wm + i * 16 + quad * 4 + r;
                    int h  = mfull >> 6, dd = mfull & 63;
                    int n  = wn + j * 16 + l15;
                    vt[(((size_t)b * HEADS + h) * HD + dd) * KVN + j0 + n] =
                        f2bf(acc[i][j][r]);
                }
    }
}

// ---------------------------------------------------------------------------
// Kernel 3: attention — byte-exact revert to the round-3 PASSING version:
// 64 queries/wave, grid (16,8,4), launch_bounds (256,2), LDS-staged K/V
// double-buffered, in-register softmax (swapped QK^T + cvt_pk + permlane).
// ---------------------------------------------------------------------------
__global__ __launch_bounds__(256, 2) void attn_kernel(
        const ushort_t* __restrict__ qs,   // [b][c][p], pre-scaled by 0.125*log2e
        const ushort_t* __restrict__ ks,   // [b][h][j][d]
        const ushort_t* __restrict__ vt,   // [b][h][d][j]
        ushort_t* __restrict__ ao) {       // [b][i][c]
    const int b = blockIdx.z, h = blockIdx.y;
    const int tid = threadIdx.x, wave = tid >> 6, lane = tid & 63;
    const int l15 = lane & 15, quad = lane >> 4;
    const int s7  = l15 & 7;
    const int iw = blockIdx.x * 256 + wave * 64;

    __shared__ ushort_t ldsK[2][64 * 64];
    __shared__ ushort_t ldsV[2][64 * 64];

    const ushort_t* Kh = &ks[((size_t)b * HEADS + h) * (KVN * HD)];
    const ushort_t* Vh = &vt[((size_t)b * HEADS + h) * (HD * KVN)];

    const int srow = wave * 8 + (lane >> 3);
    const int schk = (lane & 7) ^ (lane >> 3);
    const ushort_t* kp0 = Kh + srow * HD + schk * 8;
    const ushort_t* kp1 = Kh + (srow + 32) * HD + schk * 8;
    const ushort_t* vp0 = Vh + (size_t)srow * KVN + schk * 8;
    const ushort_t* vp1 = Vh + (size_t)(srow + 32) * KVN + schk * 8;

    bf16x8 bq[4][2];
    #pragma unroll
    for (int ih = 0; ih < 4; ++ih)
        #pragma unroll
        for (int kk = 0; kk < 2; ++kk) {
            ushort8 t;
            #pragma unroll
            for (int j = 0; j < 8; ++j) {
                int c = h * HD + kk * 32 + quad * 8 + j;
                int p = iw + ih * 16 + l15;
                t[j] = qs[((size_t)b * DIM + c) * HWN + p];
            }
            bq[ih][kk] = *(bf16x8*)&t;
        }

    f32x4 zero = {0.f, 0.f, 0.f, 0.f};
    f32x4 o[4][4];
    #pragma unroll
    for (int ih = 0; ih < 4; ++ih)
        #pragma unroll
        for (int nt = 0; nt < 4; ++nt) o[ih][nt] = zero;
    float ssum[4] = {0.f, 0.f, 0.f, 0.f};

    gload_lds16(kp0, &ldsK[0][wave * 512]);
    gload_lds16(kp1, &ldsK[0][wave * 512 + 2048]);
    gload_lds16(vp0, &ldsV[0][wave * 512]);
    gload_lds16(vp1, &ldsV[0][wave * 512 + 2048]);
    asm volatile("s_waitcnt vmcnt(0)" ::: "memory");
    __syncthreads();

    for (int t = 0; t < 16; ++t) {
        const int cur = t & 1;
        if (t < 15) {
            const int jn = (t + 1) * 64;
            gload_lds16(kp0 + jn * HD, &ldsK[cur ^ 1][wave * 512]);
            gload_lds16(kp1 + jn * HD, &ldsK[cur ^ 1][wave * 512 + 2048]);
            gload_lds16(vp0 + jn,      &ldsV[cur ^ 1][wave * 512]);
            gload_lds16(vp1 + jn,      &ldsV[cur ^ 1][wave * 512 + 2048]);
        }

        unsigned P2[4][4][2];
        #pragma unroll
        for (int nt = 0; nt < 4; ++nt) {
            const ushort_t* kb = &ldsK[cur][(nt * 16 + l15) * 64];
            bf16x8 bk0 = *(const bf16x8*)&kb[(quad ^ s7) * 8];
            bf16x8 bk1 = *(const bf16x8*)&kb[((quad + 4) ^ s7) * 8];
            #pragma unroll
            for (int ih = 0; ih < 4; ++ih) {
                f32x4 s = zero;
                s = __builtin_amdgcn_mfma_f32_16x16x32_bf16(bk0, bq[ih][0], s, 0, 0, 0);
                s = __builtin_amdgcn_mfma_f32_16x16x32_bf16(bk1, bq[ih][1], s, 0, 0, 0);
                float p0 = __builtin_amdgcn_exp2f(s[0]);
                float p1 = __builtin_amdgcn_exp2f(s[1]);
                float p2 = __builtin_amdgcn_exp2f(s[2]);
                float p3 = __builtin_amdgcn_exp2f(s[3]);
                ssum[ih] += (p0 + p1) + (p2 + p3);
                P2[ih][nt][0] = cvtpk(p0, p1);
                P2[ih][nt][1] = cvtpk(p2, p3);
            }
        }

        #pragma unroll
        for (int ih = 0; ih < 4; ++ih)
            #pragma unroll
            for (int bh = 0; bh < 2; ++bh)
                #pragma unroll
                for (int rp = 0; rp < 2; ++rp) {
                    pl32swap(P2[ih][bh * 2][rp], P2[ih][bh * 2 + 1][rp]);
                    pl16swap(P2[ih][bh * 2][rp], P2[ih][bh * 2 + 1][rp]);
                }
        bf16x8 bp[4][2];
        #pragma unroll
        for (int ih = 0; ih < 4; ++ih) {
            bp[ih][0] = frag4(P2[ih][0][0], P2[ih][0][1], P2[ih][1][0], P2[ih][1][1]);
            bp[ih][1] = frag4(P2[ih][2][0], P2[ih][2][1], P2[ih][3][0], P2[ih][3][1]);
        }

        #pragma unroll
        for (int nt = 0; nt < 4; ++nt) {
            const ushort_t* vb = &ldsV[cur][(nt * 16 + l15) * 64];
            bf16x8 bv0 = *(const bf16x8*)&vb[(quad ^ s7) * 8];
            bf16x8 bv1 = *(const bf16x8*)&vb[((quad + 4) ^ s7) * 8];
            #pragma unroll
            for (int ih = 0; ih < 4; ++ih) {
                o[ih][nt] = __builtin_amdgcn_mfma_f32_16x16x32_bf16(bv0, bp[ih][0], o[ih][nt], 0, 0, 0);
                o[ih][nt] = __builtin_amdgcn_mfma_f32_16x16x32_bf16(bv1, bp[ih][1], o[ih][nt], 0, 0, 0);
            }
        }

        asm volatile("s_waitcnt vmcnt(0)" ::: "memory");
        __syncthreads();
    }

    #pragma unroll
    for (int ih = 0; ih < 4; ++ih) {
        float tsum = ssum[ih];
        tsum += __shfl_xor(tsum, 16);
        tsum += __shfl_xor(tsum, 32);
        float invl = 1.0f / tsum;
        int i = iw + ih * 16 + l15;
        ushort_t* dst = &ao[((size_t)b * HWN + i) * DIM + h * HD];
        #pragma unroll
        for (int nt = 0; nt < 4; ++nt) {
            unsigned d0 = cvtpk(o[ih][nt][0] * invl, o[ih][nt][1] * invl);
            unsigned d1 = cvtpk(o[ih][nt][2] * invl, o[ih][nt][3] * invl);
            uint2v w; w[0] = d0; w[1] = d1;
            *(uint2v*)&dst[nt * 16 + quad * 4] = w;
        }
    }
}

// ---------------------------------------------------------------------------
// Kernel 4: output projection.  out[b][o][p] = sum_c Wout[o][c] * AO[b][p][c]
// ---------------------------------------------------------------------------
__global__ __launch_bounds__(256) void outproj_kernel(
        const ushort_t* __restrict__ ao, const ushort_t* __restrict__ woutb,
        float* __restrict__ out) {
    const int b  = blockIdx.z;
    const int m0 = blockIdx.y * 128;
    const int n0 = blockIdx.x * 128;

    __shared__ ushort_t shA[2][128 * 64];
    __shared__ ushort_t shB[2][128 * 64];

    const int tid  = threadIdx.x;
    const int wave = tid >> 6;
    const int lane = tid & 63;
    const int l15  = lane & 15;
    const int quad = lane >> 4;
    const int wm   = (wave >> 1) * 64;
    const int wn   = (wave & 1) * 64;
    const int r8   = lane >> 3;
    const int c8   = lane & 7;

    const ushort_t* aS[4];
    const ushort_t* bS[4];
    #pragma unroll
    for (int g = 0; g < 4; ++g) {
        int row = wave * 32 + g * 8 + r8;
        aS[g] = &woutb[(size_t)(m0 + row) * DIM + c8 * 8];
        bS[g] = &ao[((size_t)b * HWN + n0 + row) * DIM + c8 * 8];
    }
    const int ldso = wave * 32 * 64;

    f32x4 zero = {0.f, 0.f, 0.f, 0.f};
    f32x4 acc[4][4];
    #pragma unroll
    for (int i = 0; i < 4; ++i)
        #pragma unroll
        for (int j = 0; j < 4; ++j) acc[i][j] = zero;

    #pragma unroll
    for (int g = 0; g < 4; ++g) {
        gload_lds16(aS[g], &shA[0][ldso + g * 512]);
        gload_lds16(bS[g], &shB[0][ldso + g * 512]);
    }
    drain_sync();

    for (int t = 0; t < 8; ++t) {
        const int cur = t & 1;
        if (t < 7) {
            const int ko = (t + 1) * 64;
            #pragma unroll
            for (int g = 0; g < 4; ++g) {
                gload_lds16(aS[g] + ko, &shA[cur ^ 1][ldso + g * 512]);
                gload_lds16(bS[g] + ko, &shB[cur ^ 1][ldso + g * 512]);
            }
        }
        gemm_compute64(shA[cur], shB[cur], wm, wn, l15, quad, acc);
        drain_sync();
    }

    #pragma unroll
    for (int i = 0; i < 4; ++i)
        #pragma unroll
        for (int j = 0; j < 4; ++j)
            #pragma unroll
            for (int r = 0; r < 4; ++r) {
                int m = m0 + wm + i * 16 + quad * 4 + r;
                int n = n0 + wn + j * 16 + l15;
                out[((size_t)b * DIM + m) * HWN + n] = acc[i][j][r];
            }
}

// ---------------------------------------------------------------------------
extern "C" void kernel_launch(void* const* d_in, const int* in_sizes, int n_in,
                              void* d_out, int out_size, void* d_ws, size_t ws_size,
                              hipStream_t stream) {
    const float* x    = (const float*)d_in[0];  // [4][512][64][64] f32
    const float* wq   = (const float*)d_in[1];  // [512][512] f32
    const float* wkv  = (const float*)d_in[2];  // [1024][512][2][2] f32
    const float* wout = (const float*)d_in[3];  // [512][512] f32
    float* out = (float*)d_out;                 // [4][512][64][64] f32

    char* ws = (char*)d_ws;
    ushort_t* xT    = (ushort_t*)(ws);               // 16.78 MB  [b][p][c]
    ushort_t* qsb   = (ushort_t*)(ws + 16777216);    // 16.78 MB  [b][c][p]
    ushort_t* ksb   = (ushort_t*)(ws + 33554432);    //  4.19 MB  [b][h][j][d]
    ushort_t* vtb   = (ushort_t*)(ws + 37748736);    //  4.19 MB  [b][h][d][j]
    ushort_t* aob   = (ushort_t*)(ws + 41943040);    // 16.78 MB  [b][i][c]
    ushort_t* wqb   = (ushort_t*)(ws + 58720256);    //  0.52 MB
    ushort_t* wkvT  = (ushort_t*)(ws + 59244544);    //  4.19 MB  [o2][(q,c)]
    ushort_t* woutb = (ushort_t*)(ws + 63438848);    //  0.52 MB

    cvt_xT_kernel  <<<dim3(64, 8, 4), 256, 0, stream>>>(x, xT);
    cvt_kernel     <<<dim3(128),      256, 0, stream>>>(wq, wqb, 32768);
    cvt_wkvT_kernel<<<dim3(2048),     256, 0, stream>>>(wkv, wkvT);
    cvt_kernel     <<<dim3(128),      256, 0, stream>>>(wout, woutb, 32768);

    qproj_kernel  <<<dim3(32, 4, 4),  256, 0, stream>>>(xT, wqb, qsb);
    kv_kernel     <<<dim3(8, 8, 4),   256, 0, stream>>>(xT, wkvT, ksb, vtb);
    attn_kernel   <<<dim3(16, 8, 4),  256, 0, stream>>>(qsb, ksb, vtb, aob);
    outproj_kernel<<<dim3(32, 4, 4),  256, 0, stream>>>(aob, woutb, out);
}

// Round 8
// 225.085 us; speedup vs baseline: 1.0413x; 1.0413x over previous
//
#include <hip/hip_runtime.h>
#include <hip/hip_bf16.h>

typedef __bf16 bf16x8 __attribute__((ext_vector_type(8)));
typedef float f32x4 __attribute__((ext_vector_type(4)));
typedef unsigned short ushort_t;
typedef ushort_t ushort8 __attribute__((ext_vector_type(8)));
typedef unsigned uint2v __attribute__((ext_vector_type(2)));
typedef unsigned uint4v __attribute__((ext_vector_type(4)));

#define DIM 512
#define HEADS 8
#define HD 64
#define HWN 4096   // 64*64 queries per batch
#define KVN 1024   // 32*32 kv tokens per batch
#define KKV 2048   // 512*2*2 im2col K for the strided conv
#define LOG2E 1.44269504f

__device__ __forceinline__ ushort_t f2bf(float f) {
    union { float f; unsigned u; } v; v.f = f;
    unsigned r = v.u + 0x7fffu + ((v.u >> 16) & 1u);
    return (ushort_t)(r >> 16);
}

// pack two f32 -> one dword of 2 bf16 (RNE), low16 = lo
__device__ __forceinline__ unsigned cvtpk(float lo, float hi) {
    unsigned r;
    asm("v_cvt_pk_bf16_f32 %0, %1, %2" : "=v"(r) : "v"(lo), "v"(hi));
    return r;
}

__device__ __forceinline__ void pl32swap(unsigned &a, unsigned &b) {
    asm("v_permlane32_swap_b32 %0, %1" : "+v"(a), "+v"(b));
}
__device__ __forceinline__ void pl16swap(unsigned &a, unsigned &b) {
    asm("v_permlane16_swap_b32 %0, %1" : "+v"(a), "+v"(b));
}

__device__ __forceinline__ bf16x8 frag4(unsigned a, unsigned b, unsigned c, unsigned d) {
    uint4v t; t[0] = a; t[1] = b; t[2] = c; t[3] = d;
    return __builtin_bit_cast(bf16x8, t);
}

// async global->LDS, 16 B per lane; lds dest is wave-uniform base + lane*16
__device__ __forceinline__ void gload_lds16(const ushort_t* g, ushort_t* l) {
    __builtin_amdgcn_global_load_lds(
        (const __attribute__((address_space(1))) unsigned int*)(const void*)g,
        (__attribute__((address_space(3))) unsigned int*)(void*)l,
        16, 0, 0);
}

// explicit drain of outstanding global_load_lds before the barrier
__device__ __forceinline__ void drain_sync() {
    asm volatile("s_waitcnt vmcnt(0)" ::: "memory");
    __syncthreads();
}

// ---------------------------------------------------------------------------
// Kernel 0a: small f32 -> bf16 convert (wq, wout)
// ---------------------------------------------------------------------------
__global__ __launch_bounds__(256) void cvt_kernel(
        const float* __restrict__ src, ushort_t* __restrict__ dst, int n8) {
    int i = blockIdx.x * 256 + threadIdx.x;
    if (i >= n8) return;
    const float* p = &src[(size_t)i * 8];
    f32x4 v0 = *(const f32x4*)&p[0];
    f32x4 v1 = *(const f32x4*)&p[4];
    ushort8 w;
    w[0] = f2bf(v0[0]); w[1] = f2bf(v0[1]); w[2] = f2bf(v0[2]); w[3] = f2bf(v0[3]);
    w[4] = f2bf(v1[0]); w[5] = f2bf(v1[1]); w[6] = f2bf(v1[2]); w[7] = f2bf(v1[3]);
    *(ushort8*)&dst[i * 8] = w;
}

// ---------------------------------------------------------------------------
// Kernel 0b: x f32 [b][c][p] -> xT bf16 [b][p][c]   (tiled 64x64 transpose)
// ---------------------------------------------------------------------------
__global__ __launch_bounds__(256) void cvt_xT_kernel(
        const float* __restrict__ x, ushort_t* __restrict__ xT) {
    const int b  = blockIdx.z;
    const int c0 = blockIdx.y * 64;
    const int p0 = blockIdx.x * 64;
    __shared__ ushort_t tile[64 * 72];

    const int tid = threadIdx.x;
    {
        int r = tid >> 2, pc = (tid & 3) * 16;
        const float* src = &x[((size_t)b * DIM + c0 + r) * HWN + p0 + pc];
        f32x4 v0 = *(const f32x4*)&src[0];
        f32x4 v1 = *(const f32x4*)&src[4];
        f32x4 v2 = *(const f32x4*)&src[8];
        f32x4 v3 = *(const f32x4*)&src[12];
        ushort8 w0, w1;
        w0[0]=f2bf(v0[0]); w0[1]=f2bf(v0[1]); w0[2]=f2bf(v0[2]); w0[3]=f2bf(v0[3]);
        w0[4]=f2bf(v1[0]); w0[5]=f2bf(v1[1]); w0[6]=f2bf(v1[2]); w0[7]=f2bf(v1[3]);
        w1[0]=f2bf(v2[0]); w1[1]=f2bf(v2[1]); w1[2]=f2bf(v2[2]); w1[3]=f2bf(v2[3]);
        w1[4]=f2bf(v3[0]); w1[5]=f2bf(v3[1]); w1[6]=f2bf(v3[2]); w1[7]=f2bf(v3[3]);
        *(ushort8*)&tile[r * 72 + pc]     = w0;
        *(ushort8*)&tile[r * 72 + pc + 8] = w1;
    }
    __syncthreads();
    {
        int p = tid >> 2, cc = (tid & 3) * 16;
        ushort8 w0, w1;
        #pragma unroll
        for (int j = 0; j < 8; ++j) {
            w0[j] = tile[(cc + j) * 72 + p];
            w1[j] = tile[(cc + 8 + j) * 72 + p];
        }
        ushort_t* dst = &xT[((size_t)b * HWN + p0 + p) * DIM + c0 + cc];
        *(ushort8*)&dst[0] = w0;
        *(ushort8*)&dst[8] = w1;
    }
}

// ---------------------------------------------------------------------------
// Kernel 0c: wkv f32 [o2][c][di][dj] -> wkvT bf16 [o2][(di*2+dj)*512 + c]
// ---------------------------------------------------------------------------
__global__ __launch_bounds__(256) void cvt_wkvT_kernel(
        const float* __restrict__ wkv, ushort_t* __restrict__ wkvT) {
    int i = blockIdx.x * 256 + threadIdx.x;
    if (i >= 1024 * 512) return;
    int o2 = i >> 9, c = i & 511;
    f32x4 v = *(const f32x4*)&wkv[(size_t)i * 4];
    #pragma unroll
    for (int q = 0; q < 4; ++q)
        wkvT[(size_t)o2 * KKV + q * 512 + c] = f2bf(v[q]);
}

// ---------------------------------------------------------------------------
// Shared GEMM machinery: 128x128 tile, BK=64, double-buffered prefetch,
// XOR-swizzled LDS (rule #21: linear gload_lds dest + inverse-swizzled
// global source chunk (lane&7)^(lane>>3) + read offset chunk^(row&7)).
// Kills the 16-way ds_read_b128 conflict of linear 128B rows (R7: 6.34M
// conflict cycles in kv).  Per wave per K-step: 8 gloads, 16 ds_read, 32 MFMA.
// ---------------------------------------------------------------------------
__device__ __forceinline__ void gemm_compute64(
        const ushort_t* __restrict__ sA, const ushort_t* __restrict__ sB,
        int wm, int wn, int l15, int quad, f32x4 (&acc)[4][4]) {
    bf16x8 a[2][4], bb[2][4];
    #pragma unroll
    for (int kk = 0; kk < 2; ++kk)
        #pragma unroll
        for (int i = 0; i < 4; ++i) {
            int ra = wm + i * 16 + l15;
            int rb = wn + i * 16 + l15;
            a[kk][i]  = *(const bf16x8*)&sA[ra * 64 + (((kk * 4 + quad) ^ (ra & 7)) * 8)];
            bb[kk][i] = *(const bf16x8*)&sB[rb * 64 + (((kk * 4 + quad) ^ (rb & 7)) * 8)];
        }
    #pragma unroll
    for (int i = 0; i < 4; ++i)
        #pragma unroll
        for (int j = 0; j < 4; ++j) {
            acc[i][j] = __builtin_amdgcn_mfma_f32_16x16x32_bf16(a[0][i], bb[0][j], acc[i][j], 0, 0, 0);
            acc[i][j] = __builtin_amdgcn_mfma_f32_16x16x32_bf16(a[1][i], bb[1][j], acc[i][j], 0, 0, 0);
        }
}

// ---------------------------------------------------------------------------
// Kernel 1: Q projection.  Qs[b][o][p] = (0.125*log2e) * sum_c Wq[o][c]*X[c][p]
// ---------------------------------------------------------------------------
__global__ __launch_bounds__(256) void qproj_kernel(
        const ushort_t* __restrict__ xT, const ushort_t* __restrict__ wqb,
        ushort_t* __restrict__ qs) {
    const int b  = blockIdx.z;
    const int m0 = blockIdx.y * 128;
    const int n0 = blockIdx.x * 128;

    __shared__ ushort_t shA[2][128 * 64];
    __shared__ ushort_t shB[2][128 * 64];

    const int tid  = threadIdx.x;
    const int wave = tid >> 6;
    const int lane = tid & 63;
    const int l15  = lane & 15;
    const int quad = lane >> 4;
    const int wm   = (wave >> 1) * 64;
    const int wn   = (wave & 1) * 64;
    const int r8   = lane >> 3;          // row within 8-row group
    const int c8   = (lane & 7) ^ r8;    // inverse-swizzled source chunk

    const ushort_t* aS[4];
    const ushort_t* bS[4];
    #pragma unroll
    for (int g = 0; g < 4; ++g) {
        int row = wave * 32 + g * 8 + r8;
        aS[g] = &wqb[(size_t)(m0 + row) * DIM + c8 * 8];
        bS[g] = &xT[((size_t)b * HWN + n0 + row) * DIM + c8 * 8];
    }
    const int ldso = wave * 32 * 64;

    f32x4 zero = {0.f, 0.f, 0.f, 0.f};
    f32x4 acc[4][4];
    #pragma unroll
    for (int i = 0; i < 4; ++i)
        #pragma unroll
        for (int j = 0; j < 4; ++j) acc[i][j] = zero;

    #pragma unroll
    for (int g = 0; g < 4; ++g) {
        gload_lds16(aS[g], &shA[0][ldso + g * 512]);
        gload_lds16(bS[g], &shB[0][ldso + g * 512]);
    }
    drain_sync();

    for (int t = 0; t < 8; ++t) {
        const int cur = t & 1;
        if (t < 7) {
            const int ko = (t + 1) * 64;
            #pragma unroll
            for (int g = 0; g < 4; ++g) {
                gload_lds16(aS[g] + ko, &shA[cur ^ 1][ldso + g * 512]);
                gload_lds16(bS[g] + ko, &shB[cur ^ 1][ldso + g * 512]);
            }
        }
        gemm_compute64(shA[cur], shB[cur], wm, wn, l15, quad, acc);
        drain_sync();
    }

    #pragma unroll
    for (int i = 0; i < 4; ++i)
        #pragma unroll
        for (int j = 0; j < 4; ++j)
            #pragma unroll
            for (int r = 0; r < 4; ++r) {
                int m = m0 + wm + i * 16 + quad * 4 + r;
                int n = n0 + wn + j * 16 + l15;
                qs[((size_t)b * DIM + m) * HWN + n] =
                    f2bf(acc[i][j][r] * (0.125f * LOG2E));
            }
}

// ---------------------------------------------------------------------------
// Kernel 2: KV conv-GEMM.  A = wkvT [1024][2048], B = im2col-gathered xT.
// ---------------------------------------------------------------------------
__global__ __launch_bounds__(256) void kv_kernel(
        const ushort_t* __restrict__ xT, const ushort_t* __restrict__ wkvT,
        ushort_t* __restrict__ ks, ushort_t* __restrict__ vt) {
    const int b  = blockIdx.z;
    const int m0 = blockIdx.y * 128;
    const int j0 = blockIdx.x * 128;

    __shared__ ushort_t shA[2][128 * 64];
    __shared__ ushort_t shB[2][128 * 64];

    const int tid  = threadIdx.x;
    const int wave = tid >> 6;
    const int lane = tid & 63;
    const int l15  = lane & 15;
    const int quad = lane >> 4;
    const int wm   = (wave >> 1) * 64;
    const int wn   = (wave & 1) * 64;
    const int r8   = lane >> 3;
    const int c8   = (lane & 7) ^ r8;

    const ushort_t* aS[4];
    const ushort_t* bS[4];
    #pragma unroll
    for (int g = 0; g < 4; ++g) {
        int row = wave * 32 + g * 8 + r8;
        aS[g] = &wkvT[(size_t)(m0 + row) * KKV + c8 * 8];
        int jr = j0 + row;
        int y = jr >> 5, x = jr & 31;
        bS[g] = &xT[((size_t)b * HWN + 128 * y + 2 * x) * DIM + c8 * 8];
    }
    const int ldso = wave * 32 * 64;

    f32x4 zero = {0.f, 0.f, 0.f, 0.f};
    f32x4 acc[4][4];
    #pragma unroll
    for (int i = 0; i < 4; ++i)
        #pragma unroll
        for (int j = 0; j < 4; ++j) acc[i][j] = zero;

    // step t covers k' = t*64..t*64+63:  q = t>>3, kc = (t&7)*64
    #pragma unroll
    for (int g = 0; g < 4; ++g) {
        gload_lds16(aS[g], &shA[0][ldso + g * 512]);
        gload_lds16(bS[g], &shB[0][ldso + g * 512]);
    }
    drain_sync();

    for (int t = 0; t < 32; ++t) {
        const int cur = t & 1;
        if (t < 31) {
            const int tn = t + 1;
            const int qn = tn >> 3;
            const int ao = tn * 64;
            const int bo = (64 * (qn >> 1) + (qn & 1)) * DIM + (tn & 7) * 64;
            #pragma unroll
            for (int g = 0; g < 4; ++g) {
                gload_lds16(aS[g] + ao, &shA[cur ^ 1][ldso + g * 512]);
                gload_lds16(bS[g] + bo, &shB[cur ^ 1][ldso + g * 512]);
            }
        }
        gemm_compute64(shA[cur], shB[cur], wm, wn, l15, quad, acc);
        drain_sync();
    }

    if (m0 < DIM) {
        // K half: tile spans heads h0, h0+1.  Transpose passes through shA.
        ushort_t* cbuf = &shA[0][0];
        const int h0 = m0 >> 6;
        #pragma unroll
        for (int mh = 0; mh < 2; ++mh) {
            if ((wave >> 1) == mh) {
                #pragma unroll
                for (int i = 0; i < 4; ++i)
                    #pragma unroll
                    for (int j = 0; j < 4; ++j)
                        #pragma unroll
                        for (int r = 0; r < 4; ++r) {
                            int mloc = i * 16 + quad * 4 + r;      // 0..63 (= d)
                            int n    = wn + j * 16 + l15;          // 0..127
                            cbuf[n * 72 + mloc] = f2bf(acc[i][j][r]);
                        }
            }
            __syncthreads();
            {
                int n = tid >> 1, doff = (tid & 1) * 32;
                ushort8 u0 = *(const ushort8*)&cbuf[n * 72 + doff];
                ushort8 u1 = *(const ushort8*)&cbuf[n * 72 + doff + 8];
                ushort8 u2 = *(const ushort8*)&cbuf[n * 72 + doff + 16];
                ushort8 u3 = *(const ushort8*)&cbuf[n * 72 + doff + 24];
                ushort_t* dst =
                    &ks[(((size_t)b * HEADS + h0 + mh) * KVN + j0 + n) * HD + doff];
                *(ushort8*)&dst[0]  = u0;
                *(ushort8*)&dst[8]  = u1;
                *(ushort8*)&dst[16] = u2;
                *(ushort8*)&dst[24] = u3;
            }
            __syncthreads();
        }
    } else {
        #pragma unroll
        for (int i = 0; i < 4; ++i)
            #pragma unroll
            for (int j = 0; j < 4; ++j)
                #pragma unroll
                for (int r = 0; r < 4; ++r) {
                    int mfull = m0 - DIM + wm + i * 16 + quad * 4 + r;
                    int h  = mfull >> 6, dd = mfull & 63;
                    int n  = wn + j * 16 + l15;
                    vt[(((size_t)b * HEADS + h) * HD + dd) * KVN + j0 + n] =
                        f2bf(acc[i][j][r]);
                }
    }
}

// ---------------------------------------------------------------------------
// Kernel 3: attention — unchanged from the passing R3/R7 version:
// 64 queries/wave, grid (16,8,4), launch_bounds (256,2), LDS-staged K/V
// double-buffered, in-register softmax (swapped QK^T + cvt_pk + permlane).
// ---------------------------------------------------------------------------
__global__ __launch_bounds__(256, 2) void attn_kernel(
        const ushort_t* __restrict__ qs,   // [b][c][p], pre-scaled by 0.125*log2e
        const ushort_t* __restrict__ ks,   // [b][h][j][d]
        const ushort_t* __restrict__ vt,   // [b][h][d][j]
        ushort_t* __restrict__ ao) {       // [b][i][c]
    const int b = blockIdx.z, h = blockIdx.y;
    const int tid = threadIdx.x, wave = tid >> 6, lane = tid & 63;
    const int l15 = lane & 15, quad = lane >> 4;
    const int s7  = l15 & 7;
    const int iw = blockIdx.x * 256 + wave * 64;

    __shared__ ushort_t ldsK[2][64 * 64];
    __shared__ ushort_t ldsV[2][64 * 64];

    const ushort_t* Kh = &ks[((size_t)b * HEADS + h) * (KVN * HD)];
    const ushort_t* Vh = &vt[((size_t)b * HEADS + h) * (HD * KVN)];

    const int srow = wave * 8 + (lane >> 3);
    const int schk = (lane & 7) ^ (lane >> 3);
    const ushort_t* kp0 = Kh + srow * HD + schk * 8;
    const ushort_t* kp1 = Kh + (srow + 32) * HD + schk * 8;
    const ushort_t* vp0 = Vh + (size_t)srow * KVN + schk * 8;
    const ushort_t* vp1 = Vh + (size_t)(srow + 32) * KVN + schk * 8;

    bf16x8 bq[4][2];
    #pragma unroll
    for (int ih = 0; ih < 4; ++ih)
        #pragma unroll
        for (int kk = 0; kk < 2; ++kk) {
            ushort8 t;
            #pragma unroll
            for (int j = 0; j < 8; ++j) {
                int c = h * HD + kk * 32 + quad * 8 + j;
                int p = iw + ih * 16 + l15;
                t[j] = qs[((size_t)b * DIM + c) * HWN + p];
            }
            bq[ih][kk] = *(bf16x8*)&t;
        }

    f32x4 zero = {0.f, 0.f, 0.f, 0.f};
    f32x4 o[4][4];
    #pragma unroll
    for (int ih = 0; ih < 4; ++ih)
        #pragma unroll
        for (int nt = 0; nt < 4; ++nt) o[ih][nt] = zero;
    float ssum[4] = {0.f, 0.f, 0.f, 0.f};

    gload_lds16(kp0, &ldsK[0][wave * 512]);
    gload_lds16(kp1, &ldsK[0][wave * 512 + 2048]);
    gload_lds16(vp0, &ldsV[0][wave * 512]);
    gload_lds16(vp1, &ldsV[0][wave * 512 + 2048]);
    asm volatile("s_waitcnt vmcnt(0)" ::: "memory");
    __syncthreads();

    for (int t = 0; t < 16; ++t) {
        const int cur = t & 1;
        if (t < 15) {
            const int jn = (t + 1) * 64;
            gload_lds16(kp0 + jn * HD, &ldsK[cur ^ 1][wave * 512]);
            gload_lds16(kp1 + jn * HD, &ldsK[cur ^ 1][wave * 512 + 2048]);
            gload_lds16(vp0 + jn,      &ldsV[cur ^ 1][wave * 512]);
            gload_lds16(vp1 + jn,      &ldsV[cur ^ 1][wave * 512 + 2048]);
        }

        unsigned P2[4][4][2];
        #pragma unroll
        for (int nt = 0; nt < 4; ++nt) {
            const ushort_t* kb = &ldsK[cur][(nt * 16 + l15) * 64];
            bf16x8 bk0 = *(const bf16x8*)&kb[(quad ^ s7) * 8];
            bf16x8 bk1 = *(const bf16x8*)&kb[((quad + 4) ^ s7) * 8];
            #pragma unroll
            for (int ih = 0; ih < 4; ++ih) {
                f32x4 s = zero;
                s = __builtin_amdgcn_mfma_f32_16x16x32_bf16(bk0, bq[ih][0], s, 0, 0, 0);
                s = __builtin_amdgcn_mfma_f32_16x16x32_bf16(bk1, bq[ih][1], s, 0, 0, 0);
                float p0 = __builtin_amdgcn_exp2f(s[0]);
                float p1 = __builtin_amdgcn_exp2f(s[1]);
                float p2 = __builtin_amdgcn_exp2f(s[2]);
                float p3 = __builtin_amdgcn_exp2f(s[3]);
                ssum[ih] += (p0 + p1) + (p2 + p3);
                P2[ih][nt][0] = cvtpk(p0, p1);
                P2[ih][nt][1] = cvtpk(p2, p3);
            }
        }

        #pragma unroll
        for (int ih = 0; ih < 4; ++ih)
            #pragma unroll
            for (int bh = 0; bh < 2; ++bh)
                #pragma unroll
                for (int rp = 0; rp < 2; ++rp) {
                    pl32swap(P2[ih][bh * 2][rp], P2[ih][bh * 2 + 1][rp]);
                    pl16swap(P2[ih][bh * 2][rp], P2[ih][bh * 2 + 1][rp]);
                }
        bf16x8 bp[4][2];
        #pragma unroll
        for (int ih = 0; ih < 4; ++ih) {
            bp[ih][0] = frag4(P2[ih][0][0], P2[ih][0][1], P2[ih][1][0], P2[ih][1][1]);
            bp[ih][1] = frag4(P2[ih][2][0], P2[ih][2][1], P2[ih][3][0], P2[ih][3][1]);
        }

        #pragma unroll
        for (int nt = 0; nt < 4; ++nt) {
            const ushort_t* vb = &ldsV[cur][(nt * 16 + l15) * 64];
            bf16x8 bv0 = *(const bf16x8*)&vb[(quad ^ s7) * 8];
            bf16x8 bv1 = *(const bf16x8*)&vb[((quad + 4) ^ s7) * 8];
            #pragma unroll
            for (int ih = 0; ih < 4; ++ih) {
                o[ih][nt] = __builtin_amdgcn_mfma_f32_16x16x32_bf16(bv0, bp[ih][0], o[ih][nt], 0, 0, 0);
                o[ih][nt] = __builtin_amdgcn_mfma_f32_16x16x32_bf16(bv1, bp[ih][1], o[ih][nt], 0, 0, 0);
            }
        }

        asm volatile("s_waitcnt vmcnt(0)" ::: "memory");
        __syncthreads();
    }

    #pragma unroll
    for (int ih = 0; ih < 4; ++ih) {
        float tsum = ssum[ih];
        tsum += __shfl_xor(tsum, 16);
        tsum += __shfl_xor(tsum, 32);
        float invl = 1.0f / tsum;
        int i = iw + ih * 16 + l15;
        ushort_t* dst = &ao[((size_t)b * HWN + i) * DIM + h * HD];
        #pragma unroll
        for (int nt = 0; nt < 4; ++nt) {
            unsigned d0 = cvtpk(o[ih][nt][0] * invl, o[ih][nt][1] * invl);
            unsigned d1 = cvtpk(o[ih][nt][2] * invl, o[ih][nt][3] * invl);
            uint2v w; w[0] = d0; w[1] = d1;
            *(uint2v*)&dst[nt * 16 + quad * 4] = w;
        }
    }
}

// ---------------------------------------------------------------------------
// Kernel 4: output projection.  out[b][o][p] = sum_c Wout[o][c] * AO[b][p][c]
// ---------------------------------------------------------------------------
__global__ __launch_bounds__(256) void outproj_kernel(
        const ushort_t* __restrict__ ao, const ushort_t* __restrict__ woutb,
        float* __restrict__ out) {
    const int b  = blockIdx.z;
    const int m0 = blockIdx.y * 128;
    const int n0 = blockIdx.x * 128;

    __shared__ ushort_t shA[2][128 * 64];
    __shared__ ushort_t shB[2][128 * 64];

    const int tid  = threadIdx.x;
    const int wave = tid >> 6;
    const int lane = tid & 63;
    const int l15  = lane & 15;
    const int quad = lane >> 4;
    const int wm   = (wave >> 1) * 64;
    const int wn   = (wave & 1) * 64;
    const int r8   = lane >> 3;
    const int c8   = (lane & 7) ^ r8;

    const ushort_t* aS[4];
    const ushort_t* bS[4];
    #pragma unroll
    for (int g = 0; g < 4; ++g) {
        int row = wave * 32 + g * 8 + r8;
        aS[g] = &woutb[(size_t)(m0 + row) * DIM + c8 * 8];
        bS[g] = &ao[((size_t)b * HWN + n0 + row) * DIM + c8 * 8];
    }
    const int ldso = wave * 32 * 64;

    f32x4 zero = {0.f, 0.f, 0.f, 0.f};
    f32x4 acc[4][4];
    #pragma unroll
    for (int i = 0; i < 4; ++i)
        #pragma unroll
        for (int j = 0; j < 4; ++j) acc[i][j] = zero;

    #pragma unroll
    for (int g = 0; g < 4; ++g) {
        gload_lds16(aS[g], &shA[0][ldso + g * 512]);
        gload_lds16(bS[g], &shB[0][ldso + g * 512]);
    }
    drain_sync();

    for (int t = 0; t < 8; ++t) {
        const int cur = t & 1;
        if (t < 7) {
            const int ko = (t + 1) * 64;
            #pragma unroll
            for (int g = 0; g < 4; ++g) {
                gload_lds16(aS[g] + ko, &shA[cur ^ 1][ldso + g * 512]);
                gload_lds16(bS[g] + ko, &shB[cur ^ 1][ldso + g * 512]);
            }
        }
        gemm_compute64(shA[cur], shB[cur], wm, wn, l15, quad, acc);
        drain_sync();
    }

    #pragma unroll
    for (int i = 0; i < 4; ++i)
        #pragma unroll
        for (int j = 0; j < 4; ++j)
            #pragma unroll
            for (int r = 0; r < 4; ++r) {
                int m = m0 + wm + i * 16 + quad * 4 + r;
                int n = n0 + wn + j * 16 + l15;
                out[((size_t)b * DIM + m) * HWN + n] = acc[i][j][r];
            }
}

// ---------------------------------------------------------------------------
extern "C" void kernel_launch(void* const* d_in, const int* in_sizes, int n_in,
                              void* d_out, int out_size, void* d_ws, size_t ws_size,
                              hipStream_t stream) {
    const float* x    = (const float*)d_in[0];  // [4][512][64][64] f32
    const float* wq   = (const float*)d_in[1];  // [512][512] f32
    const float* wkv  = (const float*)d_in[2];  // [1024][512][2][2] f32
    const float* wout = (const float*)d_in[3];  // [512][512] f32
    float* out = (float*)d_out;                 // [4][512][64][64] f32

    char* ws = (char*)d_ws;
    ushort_t* xT    = (ushort_t*)(ws);               // 16.78 MB  [b][p][c]
    ushort_t* qsb   = (ushort_t*)(ws + 16777216);    // 16.78 MB  [b][c][p]
    ushort_t* ksb   = (ushort_t*)(ws + 33554432);    //  4.19 MB  [b][h][j][d]
    ushort_t* vtb   = (ushort_t*)(ws + 37748736);    //  4.19 MB  [b][h][d][j]
    ushort_t* aob   = (ushort_t*)(ws + 41943040);    // 16.78 MB  [b][i][c]
    ushort_t* wqb   = (ushort_t*)(ws + 58720256);    //  0.52 MB
    ushort_t* wkvT  = (ushort_t*)(ws + 59244544);    //  4.19 MB  [o2][(q,c)]
    ushort_t* woutb = (ushort_t*)(ws + 63438848);    //  0.52 MB

    cvt_xT_kernel  <<<dim3(64, 8, 4), 256, 0, stream>>>(x, xT);
    cvt_kernel     <<<dim3(128),      256, 0, stream>>>(wq, wqb, 32768);
    cvt_wkvT_kernel<<<dim3(2048),     256, 0, stream>>>(wkv, wkvT);
    cvt_kernel     <<<dim3(128),      256, 0, stream>>>(wout, woutb, 32768);

    qproj_kernel  <<<dim3(32, 4, 4),  256, 0, stream>>>(xT, wqb, qsb);
    kv_kernel     <<<dim3(8, 8, 4),   256, 0, stream>>>(xT, wkvT, ksb, vtb);
    attn_kernel   <<<dim3(16, 8, 4),  256, 0, stream>>>(qsb, ksb, vtb, aob);
    outproj_kernel<<<dim3(32, 4, 4),  256, 0, stream>>>(aob, woutb, out);
}

// Round 9
// 207.813 us; speedup vs baseline: 1.1279x; 1.0831x over previous
//
#include <hip/hip_runtime.h>
#include <hip/hip_bf16.h>

typedef __bf16 bf16x8 __attribute__((ext_vector_type(8)));
typedef float f32x4 __attribute__((ext_vector_type(4)));
typedef unsigned short ushort_t;
typedef ushort_t ushort8 __attribute__((ext_vector_type(8)));
typedef unsigned uint2v __attribute__((ext_vector_type(2)));
typedef unsigned uint4v __attribute__((ext_vector_type(4)));

#define DIM 512
#define HEADS 8
#define HD 64
#define HWN 4096   // 64*64 queries per batch
#define KVN 1024   // 32*32 kv tokens per batch
#define KKV 2048   // 512*2*2 im2col K for the strided conv
#define LOG2E 1.44269504f

__device__ __forceinline__ ushort_t f2bf(float f) {
    union { float f; unsigned u; } v; v.f = f;
    unsigned r = v.u + 0x7fffu + ((v.u >> 16) & 1u);
    return (ushort_t)(r >> 16);
}

// pack two f32 -> one dword of 2 bf16 (RNE), low16 = lo
__device__ __forceinline__ unsigned cvtpk(float lo, float hi) {
    unsigned r;
    asm("v_cvt_pk_bf16_f32 %0, %1, %2" : "=v"(r) : "v"(lo), "v"(hi));
    return r;
}

__device__ __forceinline__ void pl32swap(unsigned &a, unsigned &b) {
    asm("v_permlane32_swap_b32 %0, %1" : "+v"(a), "+v"(b));
}
__device__ __forceinline__ void pl16swap(unsigned &a, unsigned &b) {
    asm("v_permlane16_swap_b32 %0, %1" : "+v"(a), "+v"(b));
}

__device__ __forceinline__ bf16x8 frag4(unsigned a, unsigned b, unsigned c, unsigned d) {
    uint4v t; t[0] = a; t[1] = b; t[2] = c; t[3] = d;
    return __builtin_bit_cast(bf16x8, t);
}

// async global->LDS, 16 B per lane; lds dest is wave-uniform base + lane*16
__device__ __forceinline__ void gload_lds16(const ushort_t* g, ushort_t* l) {
    __builtin_amdgcn_global_load_lds(
        (const __attribute__((address_space(1))) unsigned int*)(const void*)g,
        (__attribute__((address_space(3))) unsigned int*)(void*)l,
        16, 0, 0);
}

// explicit drain of outstanding global_load_lds before the barrier
__device__ __forceinline__ void drain_sync() {
    asm volatile("s_waitcnt vmcnt(0)" ::: "memory");
    __syncthreads();
}

// ---------------------------------------------------------------------------
// Kernel 0a: small f32 -> bf16 convert (wq, wout)
// ---------------------------------------------------------------------------
__global__ __launch_bounds__(256) void cvt_kernel(
        const float* __restrict__ src, ushort_t* __restrict__ dst, int n8) {
    int i = blockIdx.x * 256 + threadIdx.x;
    if (i >= n8) return;
    const float* p = &src[(size_t)i * 8];
    f32x4 v0 = *(const f32x4*)&p[0];
    f32x4 v1 = *(const f32x4*)&p[4];
    ushort8 w;
    w[0] = f2bf(v0[0]); w[1] = f2bf(v0[1]); w[2] = f2bf(v0[2]); w[3] = f2bf(v0[3]);
    w[4] = f2bf(v1[0]); w[5] = f2bf(v1[1]); w[6] = f2bf(v1[2]); w[7] = f2bf(v1[3]);
    *(ushort8*)&dst[i * 8] = w;
}

// ---------------------------------------------------------------------------
// Kernel 0b: x f32 [b][c][p] -> xT bf16 [b][p][c]   (tiled 64x64 transpose)
// ---------------------------------------------------------------------------
__global__ __launch_bounds__(256) void cvt_xT_kernel(
        const float* __restrict__ x, ushort_t* __restrict__ xT) {
    const int b  = blockIdx.z;
    const int c0 = blockIdx.y * 64;
    const int p0 = blockIdx.x * 64;
    __shared__ ushort_t tile[64 * 72];

    const int tid = threadIdx.x;
    {
        int r = tid >> 2, pc = (tid & 3) * 16;
        const float* src = &x[((size_t)b * DIM + c0 + r) * HWN + p0 + pc];
        f32x4 v0 = *(const f32x4*)&src[0];
        f32x4 v1 = *(const f32x4*)&src[4];
        f32x4 v2 = *(const f32x4*)&src[8];
        f32x4 v3 = *(const f32x4*)&src[12];
        ushort8 w0, w1;
        w0[0]=f2bf(v0[0]); w0[1]=f2bf(v0[1]); w0[2]=f2bf(v0[2]); w0[3]=f2bf(v0[3]);
        w0[4]=f2bf(v1[0]); w0[5]=f2bf(v1[1]); w0[6]=f2bf(v1[2]); w0[7]=f2bf(v1[3]);
        w1[0]=f2bf(v2[0]); w1[1]=f2bf(v2[1]); w1[2]=f2bf(v2[2]); w1[3]=f2bf(v2[3]);
        w1[4]=f2bf(v3[0]); w1[5]=f2bf(v3[1]); w1[6]=f2bf(v3[2]); w1[7]=f2bf(v3[3]);
        *(ushort8*)&tile[r * 72 + pc]     = w0;
        *(ushort8*)&tile[r * 72 + pc + 8] = w1;
    }
    __syncthreads();
    {
        int p = tid >> 2, cc = (tid & 3) * 16;
        ushort8 w0, w1;
        #pragma unroll
        for (int j = 0; j < 8; ++j) {
            w0[j] = tile[(cc + j) * 72 + p];
            w1[j] = tile[(cc + 8 + j) * 72 + p];
        }
        ushort_t* dst = &xT[((size_t)b * HWN + p0 + p) * DIM + c0 + cc];
        *(ushort8*)&dst[0] = w0;
        *(ushort8*)&dst[8] = w1;
    }
}

// ---------------------------------------------------------------------------
// Kernel 0c: wkv f32 [o2][c][di][dj] -> wkvT bf16 [o2][(di*2+dj)*512 + c]
// ---------------------------------------------------------------------------
__global__ __launch_bounds__(256) void cvt_wkvT_kernel(
        const float* __restrict__ wkv, ushort_t* __restrict__ wkvT) {
    int i = blockIdx.x * 256 + threadIdx.x;
    if (i >= 1024 * 512) return;
    int o2 = i >> 9, c = i & 511;
    f32x4 v = *(const f32x4*)&wkv[(size_t)i * 4];
    #pragma unroll
    for (int q = 0; q < 4; ++q)
        wkvT[(size_t)o2 * KKV + q * 512 + c] = f2bf(v[q]);
}

// ---------------------------------------------------------------------------
// Shared GEMM machinery: 128x128 tile, BK=64, double-buffered prefetch,
// XOR-swizzled LDS (rule #21).  Used by qproj / outproj.
// ---------------------------------------------------------------------------
__device__ __forceinline__ void gemm_compute64(
        const ushort_t* __restrict__ sA, const ushort_t* __restrict__ sB,
        int wm, int wn, int l15, int quad, f32x4 (&acc)[4][4]) {
    bf16x8 a[2][4], bb[2][4];
    #pragma unroll
    for (int kk = 0; kk < 2; ++kk)
        #pragma unroll
        for (int i = 0; i < 4; ++i) {
            int ra = wm + i * 16 + l15;
            int rb = wn + i * 16 + l15;
            a[kk][i]  = *(const bf16x8*)&sA[ra * 64 + (((kk * 4 + quad) ^ (ra & 7)) * 8)];
            bb[kk][i] = *(const bf16x8*)&sB[rb * 64 + (((kk * 4 + quad) ^ (rb & 7)) * 8)];
        }
    #pragma unroll
    for (int i = 0; i < 4; ++i)
        #pragma unroll
        for (int j = 0; j < 4; ++j) {
            acc[i][j] = __builtin_amdgcn_mfma_f32_16x16x32_bf16(a[0][i], bb[0][j], acc[i][j], 0, 0, 0);
            acc[i][j] = __builtin_amdgcn_mfma_f32_16x16x32_bf16(a[1][i], bb[1][j], acc[i][j], 0, 0, 0);
        }
}

// ---------------------------------------------------------------------------
// Kernel 1: Q projection.  Qs[b][o][p] = (0.125*log2e) * sum_c Wq[o][c]*X[c][p]
// ---------------------------------------------------------------------------
__global__ __launch_bounds__(256) void qproj_kernel(
        const ushort_t* __restrict__ xT, const ushort_t* __restrict__ wqb,
        ushort_t* __restrict__ qs) {
    const int b  = blockIdx.z;
    const int m0 = blockIdx.y * 128;
    const int n0 = blockIdx.x * 128;

    __shared__ ushort_t shA[2][128 * 64];
    __shared__ ushort_t shB[2][128 * 64];

    const int tid  = threadIdx.x;
    const int wave = tid >> 6;
    const int lane = tid & 63;
    const int l15  = lane & 15;
    const int quad = lane >> 4;
    const int wm   = (wave >> 1) * 64;
    const int wn   = (wave & 1) * 64;
    const int r8   = lane >> 3;          // row within 8-row group
    const int c8   = (lane & 7) ^ r8;    // inverse-swizzled source chunk

    const ushort_t* aS[4];
    const ushort_t* bS[4];
    #pragma unroll
    for (int g = 0; g < 4; ++g) {
        int row = wave * 32 + g * 8 + r8;
        aS[g] = &wqb[(size_t)(m0 + row) * DIM + c8 * 8];
        bS[g] = &xT[((size_t)b * HWN + n0 + row) * DIM + c8 * 8];
    }
    const int ldso = wave * 32 * 64;

    f32x4 zero = {0.f, 0.f, 0.f, 0.f};
    f32x4 acc[4][4];
    #pragma unroll
    for (int i = 0; i < 4; ++i)
        #pragma unroll
        for (int j = 0; j < 4; ++j) acc[i][j] = zero;

    #pragma unroll
    for (int g = 0; g < 4; ++g) {
        gload_lds16(aS[g], &shA[0][ldso + g * 512]);
        gload_lds16(bS[g], &shB[0][ldso + g * 512]);
    }
    drain_sync();

    for (int t = 0; t < 8; ++t) {
        const int cur = t & 1;
        if (t < 7) {
            const int ko = (t + 1) * 64;
            #pragma unroll
            for (int g = 0; g < 4; ++g) {
                gload_lds16(aS[g] + ko, &shA[cur ^ 1][ldso + g * 512]);
                gload_lds16(bS[g] + ko, &shB[cur ^ 1][ldso + g * 512]);
            }
        }
        gemm_compute64(shA[cur], shB[cur], wm, wn, l15, quad, acc);
        drain_sync();
    }

    #pragma unroll
    for (int i = 0; i < 4; ++i)
        #pragma unroll
        for (int j = 0; j < 4; ++j)
            #pragma unroll
            for (int r = 0; r < 4; ++r) {
                int m = m0 + wm + i * 16 + quad * 4 + r;
                int n = n0 + wn + j * 16 + l15;
                qs[((size_t)b * DIM + m) * HWN + n] =
                    f2bf(acc[i][j][r] * (0.125f * LOG2E));
            }
}

// ---------------------------------------------------------------------------
// Kernel 2: KV conv-GEMM, 64x128 tiles for TLP (R8 showed 1 block/CU leaves
// the ~3900cy/step drain latency unhidden; 512 blocks = 2/CU overlaps it).
// A = wkvT rows [64], B = im2col-gathered xT tokens [128].  Same 2-buffer
// drain_sync structure as R8; same rule-21 swizzle.  M=64 aligns each tile
// to a single head -> one-pass transpose epilogue for the K half.
// ---------------------------------------------------------------------------
__global__ __launch_bounds__(256) void kv_kernel(
        const ushort_t* __restrict__ xT, const ushort_t* __restrict__ wkvT,
        ushort_t* __restrict__ ks, ushort_t* __restrict__ vt) {
    const int b  = blockIdx.z;
    const int m0 = blockIdx.y * 64;       // o2 rows (0..960)
    const int j0 = blockIdx.x * 128;      // tokens

    __shared__ ushort_t shA[2][64 * 64];    // 16 KB
    __shared__ ushort_t shB[2][128 * 64];   // 32 KB

    const int tid  = threadIdx.x;
    const int wave = tid >> 6;
    const int lane = tid & 63;
    const int l15  = lane & 15;
    const int quad = lane >> 4;
    const int wm   = (wave >> 1) * 32;     // 2M x 2N wave layout: wave owns 32x64
    const int wn   = (wave & 1) * 64;
    const int r8   = lane >> 3;
    const int c8   = (lane & 7) ^ r8;

    // A staging: wave covers 16 rows (2 gloads); B: 32 rows (4 gloads)
    const ushort_t* aS[2];
    #pragma unroll
    for (int g = 0; g < 2; ++g) {
        int row = wave * 16 + g * 8 + r8;
        aS[g] = &wkvT[(size_t)(m0 + row) * KKV + c8 * 8];
    }
    const ushort_t* bS[4];
    #pragma unroll
    for (int g = 0; g < 4; ++g) {
        int row = wave * 32 + g * 8 + r8;
        int jr = j0 + row;
        int y = jr >> 5, x = jr & 31;
        bS[g] = &xT[((size_t)b * HWN + 128 * y + 2 * x) * DIM + c8 * 8];
    }
    const int ldsoA = wave * 16 * 64;
    const int ldsoB = wave * 32 * 64;

    f32x4 zero = {0.f, 0.f, 0.f, 0.f};
    f32x4 acc[2][4];
    #pragma unroll
    for (int i = 0; i < 2; ++i)
        #pragma unroll
        for (int j = 0; j < 4; ++j) acc[i][j] = zero;

    // step t covers k' = t*64..t*64+63:  q = t>>3, kc = (t&7)*64
    #pragma unroll
    for (int g = 0; g < 2; ++g)
        gload_lds16(aS[g], &shA[0][ldsoA + g * 512]);
    #pragma unroll
    for (int g = 0; g < 4; ++g)
        gload_lds16(bS[g], &shB[0][ldsoB + g * 512]);
    drain_sync();

    for (int t = 0; t < 32; ++t) {
        const int cur = t & 1;
        if (t < 31) {
            const int tn = t + 1;
            const int qn = tn >> 3;
            const int ao = tn * 64;
            const int bo = (64 * (qn >> 1) + (qn & 1)) * DIM + (tn & 7) * 64;
            #pragma unroll
            for (int g = 0; g < 2; ++g)
                gload_lds16(aS[g] + ao, &shA[cur ^ 1][ldsoA + g * 512]);
            #pragma unroll
            for (int g = 0; g < 4; ++g)
                gload_lds16(bS[g] + bo, &shB[cur ^ 1][ldsoB + g * 512]);
        }
        {
            bf16x8 a[2][2], bb[2][4];
            #pragma unroll
            for (int kk = 0; kk < 2; ++kk) {
                #pragma unroll
                for (int i = 0; i < 2; ++i) {
                    int ra = wm + i * 16 + l15;
                    a[kk][i] = *(const bf16x8*)&shA[cur][ra * 64 + (((kk * 4 + quad) ^ (ra & 7)) * 8)];
                }
                #pragma unroll
                for (int j = 0; j < 4; ++j) {
                    int rb = wn + j * 16 + l15;
                    bb[kk][j] = *(const bf16x8*)&shB[cur][rb * 64 + (((kk * 4 + quad) ^ (rb & 7)) * 8)];
                }
            }
            #pragma unroll
            for (int i = 0; i < 2; ++i)
                #pragma unroll
                for (int j = 0; j < 4; ++j) {
                    acc[i][j] = __builtin_amdgcn_mfma_f32_16x16x32_bf16(a[0][i], bb[0][j], acc[i][j], 0, 0, 0);
                    acc[i][j] = __builtin_amdgcn_mfma_f32_16x16x32_bf16(a[1][i], bb[1][j], acc[i][j], 0, 0, 0);
                }
        }
        drain_sync();
    }

    if (m0 < DIM) {
        // K half: single head h, local m = d (0..63).  One transpose pass
        // through shB (32 KB >= 128*72*2B = 18 KB).
        const int h = m0 >> 6;
        ushort_t* cbuf = &shB[0][0];
        #pragma unroll
        for (int i = 0; i < 2; ++i)
            #pragma unroll
            for (int j = 0; j < 4; ++j)
                #pragma unroll
                for (int r = 0; r < 4; ++r) {
                    int m = wm + i * 16 + quad * 4 + r;    // d 0..63
                    int n = wn + j * 16 + l15;             // 0..127
                    cbuf[n * 72 + m] = f2bf(acc[i][j][r]);
                }
        __syncthreads();
        {
            int n = tid >> 1, doff = (tid & 1) * 32;
            ushort8 u0 = *(const ushort8*)&cbuf[n * 72 + doff];
            ushort8 u1 = *(const ushort8*)&cbuf[n * 72 + doff + 8];
            ushort8 u2 = *(const ushort8*)&cbuf[n * 72 + doff + 16];
            ushort8 u3 = *(const ushort8*)&cbuf[n * 72 + doff + 24];
            ushort_t* dst =
                &ks[(((size_t)b * HEADS + h) * KVN + j0 + n) * HD + doff];
            *(ushort8*)&dst[0]  = u0;
            *(ushort8*)&dst[8]  = u1;
            *(ushort8*)&dst[16] = u2;
            *(ushort8*)&dst[24] = u3;
        }
    } else {
        const int h = (m0 - DIM) >> 6;
        #pragma unroll
        for (int i = 0; i < 2; ++i)
            #pragma unroll
            for (int j = 0; j < 4; ++j)
                #pragma unroll
                for (int r = 0; r < 4; ++r) {
                    int dd = wm + i * 16 + quad * 4 + r;   // 0..63
                    int n  = wn + j * 16 + l15;            // 0..127
                    vt[(((size_t)b * HEADS + h) * HD + dd) * KVN + j0 + n] =
                        f2bf(acc[i][j][r]);
                }
    }
}

// ---------------------------------------------------------------------------
// Kernel 3: attention — unchanged from the passing R3/R7/R8 version:
// 64 queries/wave, grid (16,8,4), launch_bounds (256,2), LDS-staged K/V
// double-buffered, in-register softmax (swapped QK^T + cvt_pk + permlane).
// ---------------------------------------------------------------------------
__global__ __launch_bounds__(256, 2) void attn_kernel(
        const ushort_t* __restrict__ qs,   // [b][c][p], pre-scaled by 0.125*log2e
        const ushort_t* __restrict__ ks,   // [b][h][j][d]
        const ushort_t* __restrict__ vt,   // [b][h][d][j]
        ushort_t* __restrict__ ao) {       // [b][i][c]
    const int b = blockIdx.z, h = blockIdx.y;
    const int tid = threadIdx.x, wave = tid >> 6, lane = tid & 63;
    const int l15 = lane & 15, quad = lane >> 4;
    const int s7  = l15 & 7;
    const int iw = blockIdx.x * 256 + wave * 64;

    __shared__ ushort_t ldsK[2][64 * 64];
    __shared__ ushort_t ldsV[2][64 * 64];

    const ushort_t* Kh = &ks[((size_t)b * HEADS + h) * (KVN * HD)];
    const ushort_t* Vh = &vt[((size_t)b * HEADS + h) * (HD * KVN)];

    const int srow = wave * 8 + (lane >> 3);
    const int schk = (lane & 7) ^ (lane >> 3);
    const ushort_t* kp0 = Kh + srow * HD + schk * 8;
    const ushort_t* kp1 = Kh + (srow + 32) * HD + schk * 8;
    const ushort_t* vp0 = Vh + (size_t)srow * KVN + schk * 8;
    const ushort_t* vp1 = Vh + (size_t)(srow + 32) * KVN + schk * 8;

    bf16x8 bq[4][2];
    #pragma unroll
    for (int ih = 0; ih < 4; ++ih)
        #pragma unroll
        for (int kk = 0; kk < 2; ++kk) {
            ushort8 t;
            #pragma unroll
            for (int j = 0; j < 8; ++j) {
                int c = h * HD + kk * 32 + quad * 8 + j;
                int p = iw + ih * 16 + l15;
                t[j] = qs[((size_t)b * DIM + c) * HWN + p];
            }
            bq[ih][kk] = *(bf16x8*)&t;
        }

    f32x4 zero = {0.f, 0.f, 0.f, 0.f};
    f32x4 o[4][4];
    #pragma unroll
    for (int ih = 0; ih < 4; ++ih)
        #pragma unroll
        for (int nt = 0; nt < 4; ++nt) o[ih][nt] = zero;
    float ssum[4] = {0.f, 0.f, 0.f, 0.f};

    gload_lds16(kp0, &ldsK[0][wave * 512]);
    gload_lds16(kp1, &ldsK[0][wave * 512 + 2048]);
    gload_lds16(vp0, &ldsV[0][wave * 512]);
    gload_lds16(vp1, &ldsV[0][wave * 512 + 2048]);
    asm volatile("s_waitcnt vmcnt(0)" ::: "memory");
    __syncthreads();

    for (int t = 0; t < 16; ++t) {
        const int cur = t & 1;
        if (t < 15) {
            const int jn = (t + 1) * 64;
            gload_lds16(kp0 + jn * HD, &ldsK[cur ^ 1][wave * 512]);
            gload_lds16(kp1 + jn * HD, &ldsK[cur ^ 1][wave * 512 + 2048]);
            gload_lds16(vp0 + jn,      &ldsV[cur ^ 1][wave * 512]);
            gload_lds16(vp1 + jn,      &ldsV[cur ^ 1][wave * 512 + 2048]);
        }

        unsigned P2[4][4][2];
        #pragma unroll
        for (int nt = 0; nt < 4; ++nt) {
            const ushort_t* kb = &ldsK[cur][(nt * 16 + l15) * 64];
            bf16x8 bk0 = *(const bf16x8*)&kb[(quad ^ s7) * 8];
            bf16x8 bk1 = *(const bf16x8*)&kb[((quad + 4) ^ s7) * 8];
            #pragma unroll
            for (int ih = 0; ih < 4; ++ih) {
                f32x4 s = zero;
                s = __builtin_amdgcn_mfma_f32_16x16x32_bf16(bk0, bq[ih][0], s, 0, 0, 0);
                s = __builtin_amdgcn_mfma_f32_16x16x32_bf16(bk1, bq[ih][1], s, 0, 0, 0);
                float p0 = __builtin_amdgcn_exp2f(s[0]);
                float p1 = __builtin_amdgcn_exp2f(s[1]);
                float p2 = __builtin_amdgcn_exp2f(s[2]);
                float p3 = __builtin_amdgcn_exp2f(s[3]);
                ssum[ih] += (p0 + p1) + (p2 + p3);
                P2[ih][nt][0] = cvtpk(p0, p1);
                P2[ih][nt][1] = cvtpk(p2, p3);
            }
        }

        #pragma unroll
        for (int ih = 0; ih < 4; ++ih)
            #pragma unroll
            for (int bh = 0; bh < 2; ++bh)
                #pragma unroll
                for (int rp = 0; rp < 2; ++rp) {
                    pl32swap(P2[ih][bh * 2][rp], P2[ih][bh * 2 + 1][rp]);
                    pl16swap(P2[ih][bh * 2][rp], P2[ih][bh * 2 + 1][rp]);
                }
        bf16x8 bp[4][2];
        #pragma unroll
        for (int ih = 0; ih < 4; ++ih) {
            bp[ih][0] = frag4(P2[ih][0][0], P2[ih][0][1], P2[ih][1][0], P2[ih][1][1]);
            bp[ih][1] = frag4(P2[ih][2][0], P2[ih][2][1], P2[ih][3][0], P2[ih][3][1]);
        }

        #pragma unroll
        for (int nt = 0; nt < 4; ++nt) {
            const ushort_t* vb = &ldsV[cur][(nt * 16 + l15) * 64];
            bf16x8 bv0 = *(const bf16x8*)&vb[(quad ^ s7) * 8];
            bf16x8 bv1 = *(const bf16x8*)&vb[((quad + 4) ^ s7) * 8];
            #pragma unroll
            for (int ih = 0; ih < 4; ++ih) {
                o[ih][nt] = __builtin_amdgcn_mfma_f32_16x16x32_bf16(bv0, bp[ih][0], o[ih][nt], 0, 0, 0);
                o[ih][nt] = __builtin_amdgcn_mfma_f32_16x16x32_bf16(bv1, bp[ih][1], o[ih][nt], 0, 0, 0);
            }
        }

        asm volatile("s_waitcnt vmcnt(0)" ::: "memory");
        __syncthreads();
    }

    #pragma unroll
    for (int ih = 0; ih < 4; ++ih) {
        float tsum = ssum[ih];
        tsum += __shfl_xor(tsum, 16);
        tsum += __shfl_xor(tsum, 32);
        float invl = 1.0f / tsum;
        int i = iw + ih * 16 + l15;
        ushort_t* dst = &ao[((size_t)b * HWN + i) * DIM + h * HD];
        #pragma unroll
        for (int nt = 0; nt < 4; ++nt) {
            unsigned d0 = cvtpk(o[ih][nt][0] * invl, o[ih][nt][1] * invl);
            unsigned d1 = cvtpk(o[ih][nt][2] * invl, o[ih][nt][3] * invl);
            uint2v w; w[0] = d0; w[1] = d1;
            *(uint2v*)&dst[nt * 16 + quad * 4] = w;
        }
    }
}

// ---------------------------------------------------------------------------
// Kernel 4: output projection.  out[b][o][p] = sum_c Wout[o][c] * AO[b][p][c]
// ---------------------------------------------------------------------------
__global__ __launch_bounds__(256) void outproj_kernel(
        const ushort_t* __restrict__ ao, const ushort_t* __restrict__ woutb,
        float* __restrict__ out) {
    const int b  = blockIdx.z;
    const int m0 = blockIdx.y * 128;
    const int n0 = blockIdx.x * 128;

    __shared__ ushort_t shA[2][128 * 64];
    __shared__ ushort_t shB[2][128 * 64];

    const int tid  = threadIdx.x;
    const int wave = tid >> 6;
    const int lane = tid & 63;
    const int l15  = lane & 15;
    const int quad = lane >> 4;
    const int wm   = (wave >> 1) * 64;
    const int wn   = (wave & 1) * 64;
    const int r8   = lane >> 3;
    const int c8   = (lane & 7) ^ r8;

    const ushort_t* aS[4];
    const ushort_t* bS[4];
    #pragma unroll
    for (int g = 0; g < 4; ++g) {
        int row = wave * 32 + g * 8 + r8;
        aS[g] = &woutb[(size_t)(m0 + row) * DIM + c8 * 8];
        bS[g] = &ao[((size_t)b * HWN + n0 + row) * DIM + c8 * 8];
    }
    const int ldso = wave * 32 * 64;

    f32x4 zero = {0.f, 0.f, 0.f, 0.f};
    f32x4 acc[4][4];
    #pragma unroll
    for (int i = 0; i < 4; ++i)
        #pragma unroll
        for (int j = 0; j < 4; ++j) acc[i][j] = zero;

    #pragma unroll
    for (int g = 0; g < 4; ++g) {
        gload_lds16(aS[g], &shA[0][ldso + g * 512]);
        gload_lds16(bS[g], &shB[0][ldso + g * 512]);
    }
    drain_sync();

    for (int t = 0; t < 8; ++t) {
        const int cur = t & 1;
        if (t < 7) {
            const int ko = (t + 1) * 64;
            #pragma unroll
            for (int g = 0; g < 4; ++g) {
                gload_lds16(aS[g] + ko, &shA[cur ^ 1][ldso + g * 512]);
                gload_lds16(bS[g] + ko, &shB[cur ^ 1][ldso + g * 512]);
            }
        }
        gemm_compute64(shA[cur], shB[cur], wm, wn, l15, quad, acc);
        drain_sync();
    }

    #pragma unroll
    for (int i = 0; i < 4; ++i)
        #pragma unroll
        for (int j = 0; j < 4; ++j)
            #pragma unroll
            for (int r = 0; r < 4; ++r) {
                int m = m0 + wm + i * 16 + quad * 4 + r;
                int n = n0 + wn + j * 16 + l15;
                out[((size_t)b * DIM + m) * HWN + n] = acc[i][j][r];
            }
}

// ---------------------------------------------------------------------------
extern "C" void kernel_launch(void* const* d_in, const int* in_sizes, int n_in,
                              void* d_out, int out_size, void* d_ws, size_t ws_size,
                              hipStream_t stream) {
    const float* x    = (const float*)d_in[0];  // [4][512][64][64] f32
    const float* wq   = (const float*)d_in[1];  // [512][512] f32
    const float* wkv  = (const float*)d_in[2];  // [1024][512][2][2] f32
    const float* wout = (const float*)d_in[3];  // [512][512] f32
    float* out = (float*)d_out;                 // [4][512][64][64] f32

    char* ws = (char*)d_ws;
    ushort_t* xT    = (ushort_t*)(ws);               // 16.78 MB  [b][p][c]
    ushort_t* qsb   = (ushort_t*)(ws + 16777216);    // 16.78 MB  [b][c][p]
    ushort_t* ksb   = (ushort_t*)(ws + 33554432);    //  4.19 MB  [b][h][j][d]
    ushort_t* vtb   = (ushort_t*)(ws + 37748736);    //  4.19 MB  [b][h][d][j]
    ushort_t* aob   = (ushort_t*)(ws + 41943040);    // 16.78 MB  [b][i][c]
    ushort_t* wqb   = (ushort_t*)(ws + 58720256);    //  0.52 MB
    ushort_t* wkvT  = (ushort_t*)(ws + 59244544);    //  4.19 MB  [o2][(q,c)]
    ushort_t* woutb = (ushort_t*)(ws + 63438848);    //  0.52 MB

    cvt_xT_kernel  <<<dim3(64, 8, 4), 256, 0, stream>>>(x, xT);
    cvt_kernel     <<<dim3(128),      256, 0, stream>>>(wq, wqb, 32768);
    cvt_wkvT_kernel<<<dim3(2048),     256, 0, stream>>>(wkv, wkvT);
    cvt_kernel     <<<dim3(128),      256, 0, stream>>>(wout, woutb, 32768);

    qproj_kernel  <<<dim3(32, 4, 4),  256, 0, stream>>>(xT, wqb, qsb);
    kv_kernel     <<<dim3(8, 16, 4),  256, 0, stream>>>(xT, wkvT, ksb, vtb);
    attn_kernel   <<<dim3(16, 8, 4),  256, 0, stream>>>(qsb, ksb, vtb, aob);
    outproj_kernel<<<dim3(32, 4, 4),  256, 0, stream>>>(aob, woutb, out);
}

// Round 10
// 199.350 us; speedup vs baseline: 1.1757x; 1.0425x over previous
//
#include <hip/hip_runtime.h>
#include <hip/hip_bf16.h>

typedef __bf16 bf16x8 __attribute__((ext_vector_type(8)));
typedef float f32x4 __attribute__((ext_vector_type(4)));
typedef unsigned short ushort_t;
typedef ushort_t ushort8 __attribute__((ext_vector_type(8)));
typedef unsigned uint2v __attribute__((ext_vector_type(2)));
typedef unsigned uint4v __attribute__((ext_vector_type(4)));

#define DIM 512
#define HEADS 8
#define HD 64
#define HWN 4096   // 64*64 queries per batch
#define KVN 1024   // 32*32 kv tokens per batch
#define KKV 2048   // 512*2*2 im2col K for the strided conv
#define LOG2E 1.44269504f

__device__ __forceinline__ ushort_t f2bf(float f) {
    union { float f; unsigned u; } v; v.f = f;
    unsigned r = v.u + 0x7fffu + ((v.u >> 16) & 1u);
    return (ushort_t)(r >> 16);
}

// pack two f32 -> one dword of 2 bf16 (RNE), low16 = lo
__device__ __forceinline__ unsigned cvtpk(float lo, float hi) {
    unsigned r;
    asm("v_cvt_pk_bf16_f32 %0, %1, %2" : "=v"(r) : "v"(lo), "v"(hi));
    return r;
}

__device__ __forceinline__ void pl32swap(unsigned &a, unsigned &b) {
    asm("v_permlane32_swap_b32 %0, %1" : "+v"(a), "+v"(b));
}
__device__ __forceinline__ void pl16swap(unsigned &a, unsigned &b) {
    asm("v_permlane16_swap_b32 %0, %1" : "+v"(a), "+v"(b));
}

__device__ __forceinline__ bf16x8 frag4(unsigned a, unsigned b, unsigned c, unsigned d) {
    uint4v t; t[0] = a; t[1] = b; t[2] = c; t[3] = d;
    return __builtin_bit_cast(bf16x8, t);
}

// async global->LDS, 16 B per lane; lds dest is wave-uniform base + lane*16
__device__ __forceinline__ void gload_lds16(const ushort_t* g, ushort_t* l) {
    __builtin_amdgcn_global_load_lds(
        (const __attribute__((address_space(1))) unsigned int*)(const void*)g,
        (__attribute__((address_space(3))) unsigned int*)(void*)l,
        16, 0, 0);
}

// explicit drain of outstanding global_load_lds before the barrier
__device__ __forceinline__ void drain_sync() {
    asm volatile("s_waitcnt vmcnt(0)" ::: "memory");
    __syncthreads();
}

// ---------------------------------------------------------------------------
// Kernel 0a: small f32 -> bf16 convert (wq, wout)
// ---------------------------------------------------------------------------
__global__ __launch_bounds__(256) void cvt_kernel(
        const float* __restrict__ src, ushort_t* __restrict__ dst, int n8) {
    int i = blockIdx.x * 256 + threadIdx.x;
    if (i >= n8) return;
    const float* p = &src[(size_t)i * 8];
    f32x4 v0 = *(const f32x4*)&p[0];
    f32x4 v1 = *(const f32x4*)&p[4];
    ushort8 w;
    w[0] = f2bf(v0[0]); w[1] = f2bf(v0[1]); w[2] = f2bf(v0[2]); w[3] = f2bf(v0[3]);
    w[4] = f2bf(v1[0]); w[5] = f2bf(v1[1]); w[6] = f2bf(v1[2]); w[7] = f2bf(v1[3]);
    *(ushort8*)&dst[i * 8] = w;
}

// ---------------------------------------------------------------------------
// Kernel 0b: x f32 [b][c][p] -> xT bf16 [b][p][c]   (tiled 64x64 transpose)
// ---------------------------------------------------------------------------
__global__ __launch_bounds__(256) void cvt_xT_kernel(
        const float* __restrict__ x, ushort_t* __restrict__ xT) {
    const int b  = blockIdx.z;
    const int c0 = blockIdx.y * 64;
    const int p0 = blockIdx.x * 64;
    __shared__ ushort_t tile[64 * 72];

    const int tid = threadIdx.x;
    {
        int r = tid >> 2, pc = (tid & 3) * 16;
        const float* src = &x[((size_t)b * DIM + c0 + r) * HWN + p0 + pc];
        f32x4 v0 = *(const f32x4*)&src[0];
        f32x4 v1 = *(const f32x4*)&src[4];
        f32x4 v2 = *(const f32x4*)&src[8];
        f32x4 v3 = *(const f32x4*)&src[12];
        ushort8 w0, w1;
        w0[0]=f2bf(v0[0]); w0[1]=f2bf(v0[1]); w0[2]=f2bf(v0[2]); w0[3]=f2bf(v0[3]);
        w0[4]=f2bf(v1[0]); w0[5]=f2bf(v1[1]); w0[6]=f2bf(v1[2]); w0[7]=f2bf(v1[3]);
        w1[0]=f2bf(v2[0]); w1[1]=f2bf(v2[1]); w1[2]=f2bf(v2[2]); w1[3]=f2bf(v2[3]);
        w1[4]=f2bf(v3[0]); w1[5]=f2bf(v3[1]); w1[6]=f2bf(v3[2]); w1[7]=f2bf(v3[3]);
        *(ushort8*)&tile[r * 72 + pc]     = w0;
        *(ushort8*)&tile[r * 72 + pc + 8] = w1;
    }
    __syncthreads();
    {
        int p = tid >> 2, cc = (tid & 3) * 16;
        ushort8 w0, w1;
        #pragma unroll
        for (int j = 0; j < 8; ++j) {
            w0[j] = tile[(cc + j) * 72 + p];
            w1[j] = tile[(cc + 8 + j) * 72 + p];
        }
        ushort_t* dst = &xT[((size_t)b * HWN + p0 + p) * DIM + c0 + cc];
        *(ushort8*)&dst[0] = w0;
        *(ushort8*)&dst[8] = w1;
    }
}

// ---------------------------------------------------------------------------
// Kernel 0c: wkv f32 [o2][c][di][dj] -> wkvT bf16 [o2][(di*2+dj)*512 + c]
// ---------------------------------------------------------------------------
__global__ __launch_bounds__(256) void cvt_wkvT_kernel(
        const float* __restrict__ wkv, ushort_t* __restrict__ wkvT) {
    int i = blockIdx.x * 256 + threadIdx.x;
    if (i >= 1024 * 512) return;
    int o2 = i >> 9, c = i & 511;
    f32x4 v = *(const f32x4*)&wkv[(size_t)i * 4];
    #pragma unroll
    for (int q = 0; q < 4; ++q)
        wkvT[(size_t)o2 * KKV + q * 512 + c] = f2bf(v[q]);
}

// ---------------------------------------------------------------------------
// 512-thread GEMM helper: 128x128 tile, BK=64, 8 waves (2M x 4N, each 64x32),
// XOR-swizzled LDS (rule #21).  Per wave per step: 12 ds_read_b128, 16 MFMA.
// ---------------------------------------------------------------------------
__device__ __forceinline__ void gemm_compute_512(
        const ushort_t* __restrict__ sA, const ushort_t* __restrict__ sB,
        int wm, int wn, int l15, int quad, f32x4 (&acc)[4][2]) {
    bf16x8 a[2][4], bb[2][2];
    #pragma unroll
    for (int kk = 0; kk < 2; ++kk) {
        #pragma unroll
        for (int i = 0; i < 4; ++i) {
            int ra = wm + i * 16 + l15;
            a[kk][i] = *(const bf16x8*)&sA[ra * 64 + (((kk * 4 + quad) ^ (ra & 7)) * 8)];
        }
        #pragma unroll
        for (int j = 0; j < 2; ++j) {
            int rb = wn + j * 16 + l15;
            bb[kk][j] = *(const bf16x8*)&sB[rb * 64 + (((kk * 4 + quad) ^ (rb & 7)) * 8)];
        }
    }
    #pragma unroll
    for (int i = 0; i < 4; ++i)
        #pragma unroll
        for (int j = 0; j < 2; ++j) {
            acc[i][j] = __builtin_amdgcn_mfma_f32_16x16x32_bf16(a[0][i], bb[0][j], acc[i][j], 0, 0, 0);
            acc[i][j] = __builtin_amdgcn_mfma_f32_16x16x32_bf16(a[1][i], bb[1][j], acc[i][j], 0, 0, 0);
        }
}

// ---------------------------------------------------------------------------
// Kernel 1: Q projection, 512-thread blocks (8 waves -> 4 waves/SIMD at
// 2 blocks/CU; R9 showed waves/SIMD is the TLP lever for the 2-phase drain).
// Qs[b][o][p] = (0.125*log2e) * sum_c Wq[o][c]*X[c][p]
// ---------------------------------------------------------------------------
__global__ __launch_bounds__(512, 4) void qproj_kernel(
        const ushort_t* __restrict__ xT, const ushort_t* __restrict__ wqb,
        ushort_t* __restrict__ qs) {
    const int b  = blockIdx.z;
    const int m0 = blockIdx.y * 128;
    const int n0 = blockIdx.x * 128;

    __shared__ ushort_t shA[2][128 * 64];
    __shared__ ushort_t shB[2][128 * 64];

    const int tid  = threadIdx.x;
    const int wave = tid >> 6;          // 0..7
    const int lane = tid & 63;
    const int l15  = lane & 15;
    const int quad = lane >> 4;
    const int wm   = (wave >> 2) * 64;  // 2 M-waves
    const int wn   = (wave & 3) * 32;   // 4 N-waves
    const int r8   = lane >> 3;
    const int c8   = (lane & 7) ^ r8;   // inverse-swizzled source chunk

    // staging: g in {0,1}: row = g*64 + wave*8 + r8 covers 0..127
    const ushort_t* aS[2];
    const ushort_t* bS[2];
    #pragma unroll
    for (int g = 0; g < 2; ++g) {
        int row = g * 64 + wave * 8 + r8;
        aS[g] = &wqb[(size_t)(m0 + row) * DIM + c8 * 8];
        bS[g] = &xT[((size_t)b * HWN + n0 + row) * DIM + c8 * 8];
    }
    const int ldso = wave * 8 * 64;     // wave-uniform dest base (+g*64*64)

    f32x4 zero = {0.f, 0.f, 0.f, 0.f};
    f32x4 acc[4][2];
    #pragma unroll
    for (int i = 0; i < 4; ++i)
        #pragma unroll
        for (int j = 0; j < 2; ++j) acc[i][j] = zero;

    #pragma unroll
    for (int g = 0; g < 2; ++g) {
        gload_lds16(aS[g], &shA[0][g * 4096 + ldso]);
        gload_lds16(bS[g], &shB[0][g * 4096 + ldso]);
    }
    drain_sync();

    for (int t = 0; t < 8; ++t) {
        const int cur = t & 1;
        if (t < 7) {
            const int ko = (t + 1) * 64;
            #pragma unroll
            for (int g = 0; g < 2; ++g) {
                gload_lds16(aS[g] + ko, &shA[cur ^ 1][g * 4096 + ldso]);
                gload_lds16(bS[g] + ko, &shB[cur ^ 1][g * 4096 + ldso]);
            }
        }
        gemm_compute_512(shA[cur], shB[cur], wm, wn, l15, quad, acc);
        drain_sync();
    }

    #pragma unroll
    for (int i = 0; i < 4; ++i)
        #pragma unroll
        for (int j = 0; j < 2; ++j)
            #pragma unroll
            for (int r = 0; r < 4; ++r) {
                int m = m0 + wm + i * 16 + quad * 4 + r;
                int n = n0 + wn + j * 16 + l15;
                qs[((size_t)b * DIM + m) * HWN + n] =
                    f2bf(acc[i][j][r] * (0.125f * LOG2E));
            }
}

// ---------------------------------------------------------------------------
// Kernel 2: KV conv-GEMM, 64x128 tiles, 512-thread blocks (8 waves 2Mx4N,
// each 32x32).  A = wkvT rows [64], B = im2col-gathered xT tokens [128].
// ---------------------------------------------------------------------------
__global__ __launch_bounds__(512, 4) void kv_kernel(
        const ushort_t* __restrict__ xT, const ushort_t* __restrict__ wkvT,
        ushort_t* __restrict__ ks, ushort_t* __restrict__ vt) {
    const int b  = blockIdx.z;
    const int m0 = blockIdx.y * 64;       // o2 rows
    const int j0 = blockIdx.x * 128;      // tokens

    __shared__ ushort_t shA[2][64 * 64];    // 16 KB
    __shared__ ushort_t shB[2][128 * 64];   // 32 KB

    const int tid  = threadIdx.x;
    const int wave = tid >> 6;
    const int lane = tid & 63;
    const int l15  = lane & 15;
    const int quad = lane >> 4;
    const int wm   = (wave >> 2) * 32;
    const int wn   = (wave & 3) * 32;
    const int r8   = lane >> 3;
    const int c8   = (lane & 7) ^ r8;

    // A staging: 1 load/thread (rows 0..63); B: 2 loads (rows 0..127)
    const ushort_t* aS = &wkvT[(size_t)(m0 + wave * 8 + r8) * KKV + c8 * 8];
    const ushort_t* bS[2];
    #pragma unroll
    for (int g = 0; g < 2; ++g) {
        int row = g * 64 + wave * 8 + r8;
        int jr = j0 + row;
        int y = jr >> 5, x = jr & 31;
        bS[g] = &xT[((size_t)b * HWN + 128 * y + 2 * x) * DIM + c8 * 8];
    }
    const int ldso = wave * 8 * 64;

    f32x4 zero = {0.f, 0.f, 0.f, 0.f};
    f32x4 acc[2][2];
    #pragma unroll
    for (int i = 0; i < 2; ++i)
        #pragma unroll
        for (int j = 0; j < 2; ++j) acc[i][j] = zero;

    // step t covers k' = t*64..t*64+63:  q = t>>3, kc = (t&7)*64
    gload_lds16(aS, &shA[0][ldso]);
    #pragma unroll
    for (int g = 0; g < 2; ++g)
        gload_lds16(bS[g], &shB[0][g * 4096 + ldso]);
    drain_sync();

    for (int t = 0; t < 32; ++t) {
        const int cur = t & 1;
        if (t < 31) {
            const int tn = t + 1;
            const int qn = tn >> 3;
            const int ao = tn * 64;
            const int bo = (64 * (qn >> 1) + (qn & 1)) * DIM + (tn & 7) * 64;
            gload_lds16(aS + ao, &shA[cur ^ 1][ldso]);
            #pragma unroll
            for (int g = 0; g < 2; ++g)
                gload_lds16(bS[g] + bo, &shB[cur ^ 1][g * 4096 + ldso]);
        }
        {
            bf16x8 a[2][2], bb[2][2];
            #pragma unroll
            for (int kk = 0; kk < 2; ++kk) {
                #pragma unroll
                for (int i = 0; i < 2; ++i) {
                    int ra = wm + i * 16 + l15;
                    a[kk][i] = *(const bf16x8*)&shA[cur][ra * 64 + (((kk * 4 + quad) ^ (ra & 7)) * 8)];
                }
                #pragma unroll
                for (int j = 0; j < 2; ++j) {
                    int rb = wn + j * 16 + l15;
                    bb[kk][j] = *(const bf16x8*)&shB[cur][rb * 64 + (((kk * 4 + quad) ^ (rb & 7)) * 8)];
                }
            }
            #pragma unroll
            for (int i = 0; i < 2; ++i)
                #pragma unroll
                for (int j = 0; j < 2; ++j) {
                    acc[i][j] = __builtin_amdgcn_mfma_f32_16x16x32_bf16(a[0][i], bb[0][j], acc[i][j], 0, 0, 0);
                    acc[i][j] = __builtin_amdgcn_mfma_f32_16x16x32_bf16(a[1][i], bb[1][j], acc[i][j], 0, 0, 0);
                }
        }
        drain_sync();
    }

    if (m0 < DIM) {
        // K half: single head h, local m = d (0..63).  One transpose pass.
        // cbuf needs 128*72 = 9216 elems; shB (contiguous 16384) holds it.
        const int h = m0 >> 6;
        ushort_t* cbuf = &shB[0][0];
        #pragma unroll
        for (int i = 0; i < 2; ++i)
            #pragma unroll
            for (int j = 0; j < 2; ++j)
                #pragma unroll
                for (int r = 0; r < 4; ++r) {
                    int m = wm + i * 16 + quad * 4 + r;    // d 0..63
                    int n = wn + j * 16 + l15;             // 0..127
                    cbuf[n * 72 + m] = f2bf(acc[i][j][r]);
                }
        __syncthreads();
        {
            int n = tid >> 2, doff = (tid & 3) * 16;
            ushort8 u0 = *(const ushort8*)&cbuf[n * 72 + doff];
            ushort8 u1 = *(const ushort8*)&cbuf[n * 72 + doff + 8];
            ushort_t* dst =
                &ks[(((size_t)b * HEADS + h) * KVN + j0 + n) * HD + doff];
            *(ushort8*)&dst[0] = u0;
            *(ushort8*)&dst[8] = u1;
        }
    } else {
        const int h = (m0 - DIM) >> 6;
        #pragma unroll
        for (int i = 0; i < 2; ++i)
            #pragma unroll
            for (int j = 0; j < 2; ++j)
                #pragma unroll
                for (int r = 0; r < 4; ++r) {
                    int dd = wm + i * 16 + quad * 4 + r;   // 0..63
                    int n  = wn + j * 16 + l15;            // 0..127
                    vt[(((size_t)b * HEADS + h) * HD + dd) * KVN + j0 + n] =
                        f2bf(acc[i][j][r]);
                }
    }
}

// ---------------------------------------------------------------------------
// Kernel 3: attention — unchanged from the passing R3/R7/R8/R9 version:
// 64 queries/wave, grid (16,8,4), launch_bounds (256,2), LDS-staged K/V
// double-buffered, in-register softmax (swapped QK^T + cvt_pk + permlane).
// ---------------------------------------------------------------------------
__global__ __launch_bounds__(256, 2) void attn_kernel(
        const ushort_t* __restrict__ qs,   // [b][c][p], pre-scaled by 0.125*log2e
        const ushort_t* __restrict__ ks,   // [b][h][j][d]
        const ushort_t* __restrict__ vt,   // [b][h][d][j]
        ushort_t* __restrict__ ao) {       // [b][i][c]
    const int b = blockIdx.z, h = blockIdx.y;
    const int tid = threadIdx.x, wave = tid >> 6, lane = tid & 63;
    const int l15 = lane & 15, quad = lane >> 4;
    const int s7  = l15 & 7;
    const int iw = blockIdx.x * 256 + wave * 64;

    __shared__ ushort_t ldsK[2][64 * 64];
    __shared__ ushort_t ldsV[2][64 * 64];

    const ushort_t* Kh = &ks[((size_t)b * HEADS + h) * (KVN * HD)];
    const ushort_t* Vh = &vt[((size_t)b * HEADS + h) * (HD * KVN)];

    const int srow = wave * 8 + (lane >> 3);
    const int schk = (lane & 7) ^ (lane >> 3);
    const ushort_t* kp0 = Kh + srow * HD + schk * 8;
    const ushort_t* kp1 = Kh + (srow + 32) * HD + schk * 8;
    const ushort_t* vp0 = Vh + (size_t)srow * KVN + schk * 8;
    const ushort_t* vp1 = Vh + (size_t)(srow + 32) * KVN + schk * 8;

    bf16x8 bq[4][2];
    #pragma unroll
    for (int ih = 0; ih < 4; ++ih)
        #pragma unroll
        for (int kk = 0; kk < 2; ++kk) {
            ushort8 t;
            #pragma unroll
            for (int j = 0; j < 8; ++j) {
                int c = h * HD + kk * 32 + quad * 8 + j;
                int p = iw + ih * 16 + l15;
                t[j] = qs[((size_t)b * DIM + c) * HWN + p];
            }
            bq[ih][kk] = *(bf16x8*)&t;
        }

    f32x4 zero = {0.f, 0.f, 0.f, 0.f};
    f32x4 o[4][4];
    #pragma unroll
    for (int ih = 0; ih < 4; ++ih)
        #pragma unroll
        for (int nt = 0; nt < 4; ++nt) o[ih][nt] = zero;
    float ssum[4] = {0.f, 0.f, 0.f, 0.f};

    gload_lds16(kp0, &ldsK[0][wave * 512]);
    gload_lds16(kp1, &ldsK[0][wave * 512 + 2048]);
    gload_lds16(vp0, &ldsV[0][wave * 512]);
    gload_lds16(vp1, &ldsV[0][wave * 512 + 2048]);
    asm volatile("s_waitcnt vmcnt(0)" ::: "memory");
    __syncthreads();

    for (int t = 0; t < 16; ++t) {
        const int cur = t & 1;
        if (t < 15) {
            const int jn = (t + 1) * 64;
            gload_lds16(kp0 + jn * HD, &ldsK[cur ^ 1][wave * 512]);
            gload_lds16(kp1 + jn * HD, &ldsK[cur ^ 1][wave * 512 + 2048]);
            gload_lds16(vp0 + jn,      &ldsV[cur ^ 1][wave * 512]);
            gload_lds16(vp1 + jn,      &ldsV[cur ^ 1][wave * 512 + 2048]);
        }

        unsigned P2[4][4][2];
        #pragma unroll
        for (int nt = 0; nt < 4; ++nt) {
            const ushort_t* kb = &ldsK[cur][(nt * 16 + l15) * 64];
            bf16x8 bk0 = *(const bf16x8*)&kb[(quad ^ s7) * 8];
            bf16x8 bk1 = *(const bf16x8*)&kb[((quad + 4) ^ s7) * 8];
            #pragma unroll
            for (int ih = 0; ih < 4; ++ih) {
                f32x4 s = zero;
                s = __builtin_amdgcn_mfma_f32_16x16x32_bf16(bk0, bq[ih][0], s, 0, 0, 0);
                s = __builtin_amdgcn_mfma_f32_16x16x32_bf16(bk1, bq[ih][1], s, 0, 0, 0);
                float p0 = __builtin_amdgcn_exp2f(s[0]);
                float p1 = __builtin_amdgcn_exp2f(s[1]);
                float p2 = __builtin_amdgcn_exp2f(s[2]);
                float p3 = __builtin_amdgcn_exp2f(s[3]);
                ssum[ih] += (p0 + p1) + (p2 + p3);
                P2[ih][nt][0] = cvtpk(p0, p1);
                P2[ih][nt][1] = cvtpk(p2, p3);
            }
        }

        #pragma unroll
        for (int ih = 0; ih < 4; ++ih)
            #pragma unroll
            for (int bh = 0; bh < 2; ++bh)
                #pragma unroll
                for (int rp = 0; rp < 2; ++rp) {
                    pl32swap(P2[ih][bh * 2][rp], P2[ih][bh * 2 + 1][rp]);
                    pl16swap(P2[ih][bh * 2][rp], P2[ih][bh * 2 + 1][rp]);
                }
        bf16x8 bp[4][2];
        #pragma unroll
        for (int ih = 0; ih < 4; ++ih) {
            bp[ih][0] = frag4(P2[ih][0][0], P2[ih][0][1], P2[ih][1][0], P2[ih][1][1]);
            bp[ih][1] = frag4(P2[ih][2][0], P2[ih][2][1], P2[ih][3][0], P2[ih][3][1]);
        }

        #pragma unroll
        for (int nt = 0; nt < 4; ++nt) {
            const ushort_t* vb = &ldsV[cur][(nt * 16 + l15) * 64];
            bf16x8 bv0 = *(const bf16x8*)&vb[(quad ^ s7) * 8];
            bf16x8 bv1 = *(const bf16x8*)&vb[((quad + 4) ^ s7) * 8];
            #pragma unroll
            for (int ih = 0; ih < 4; ++ih) {
                o[ih][nt] = __builtin_amdgcn_mfma_f32_16x16x32_bf16(bv0, bp[ih][0], o[ih][nt], 0, 0, 0);
                o[ih][nt] = __builtin_amdgcn_mfma_f32_16x16x32_bf16(bv1, bp[ih][1], o[ih][nt], 0, 0, 0);
            }
        }

        asm volatile("s_waitcnt vmcnt(0)" ::: "memory");
        __syncthreads();
    }

    #pragma unroll
    for (int ih = 0; ih < 4; ++ih) {
        float tsum = ssum[ih];
        tsum += __shfl_xor(tsum, 16);
        tsum += __shfl_xor(tsum, 32);
        float invl = 1.0f / tsum;
        int i = iw + ih * 16 + l15;
        ushort_t* dst = &ao[((size_t)b * HWN + i) * DIM + h * HD];
        #pragma unroll
        for (int nt = 0; nt < 4; ++nt) {
            unsigned d0 = cvtpk(o[ih][nt][0] * invl, o[ih][nt][1] * invl);
            unsigned d1 = cvtpk(o[ih][nt][2] * invl, o[ih][nt][3] * invl);
            uint2v w; w[0] = d0; w[1] = d1;
            *(uint2v*)&dst[nt * 16 + quad * 4] = w;
        }
    }
}

// ---------------------------------------------------------------------------
// Kernel 4: output projection, 512-thread blocks.
// out[b][o][p] = sum_c Wout[o][c] * AO[b][p][c]   (f32 output)
// ---------------------------------------------------------------------------
__global__ __launch_bounds__(512, 4) void outproj_kernel(
        const ushort_t* __restrict__ ao, const ushort_t* __restrict__ woutb,
        float* __restrict__ out) {
    const int b  = blockIdx.z;
    const int m0 = blockIdx.y * 128;
    const int n0 = blockIdx.x * 128;

    __shared__ ushort_t shA[2][128 * 64];
    __shared__ ushort_t shB[2][128 * 64];

    const int tid  = threadIdx.x;
    const int wave = tid >> 6;
    const int lane = tid & 63;
    const int l15  = lane & 15;
    const int quad = lane >> 4;
    const int wm   = (wave >> 2) * 64;
    const int wn   = (wave & 3) * 32;
    const int r8   = lane >> 3;
    const int c8   = (lane & 7) ^ r8;

    const ushort_t* aS[2];
    const ushort_t* bS[2];
    #pragma unroll
    for (int g = 0; g < 2; ++g) {
        int row = g * 64 + wave * 8 + r8;
        aS[g] = &woutb[(size_t)(m0 + row) * DIM + c8 * 8];
        bS[g] = &ao[((size_t)b * HWN + n0 + row) * DIM + c8 * 8];
    }
    const int ldso = wave * 8 * 64;

    f32x4 zero = {0.f, 0.f, 0.f, 0.f};
    f32x4 acc[4][2];
    #pragma unroll
    for (int i = 0; i < 4; ++i)
        #pragma unroll
        for (int j = 0; j < 2; ++j) acc[i][j] = zero;

    #pragma unroll
    for (int g = 0; g < 2; ++g) {
        gload_lds16(aS[g], &shA[0][g * 4096 + ldso]);
        gload_lds16(bS[g], &shB[0][g * 4096 + ldso]);
    }
    drain_sync();

    for (int t = 0; t < 8; ++t) {
        const int cur = t & 1;
        if (t < 7) {
            const int ko = (t + 1) * 64;
            #pragma unroll
            for (int g = 0; g < 2; ++g) {
                gload_lds16(aS[g] + ko, &shA[cur ^ 1][g * 4096 + ldso]);
                gload_lds16(bS[g] + ko, &shB[cur ^ 1][g * 4096 + ldso]);
            }
        }
        gemm_compute_512(shA[cur], shB[cur], wm, wn, l15, quad, acc);
        drain_sync();
    }

    #pragma unroll
    for (int i = 0; i < 4; ++i)
        #pragma unroll
        for (int j = 0; j < 2; ++j)
            #pragma unroll
            for (int r = 0; r < 4; ++r) {
                int m = m0 + wm + i * 16 + quad * 4 + r;
                int n = n0 + wn + j * 16 + l15;
                out[((size_t)b * DIM + m) * HWN + n] = acc[i][j][r];
            }
}

// ---------------------------------------------------------------------------
extern "C" void kernel_launch(void* const* d_in, const int* in_sizes, int n_in,
                              void* d_out, int out_size, void* d_ws, size_t ws_size,
                              hipStream_t stream) {
    const float* x    = (const float*)d_in[0];  // [4][512][64][64] f32
    const float* wq   = (const float*)d_in[1];  // [512][512] f32
    const float* wkv  = (const float*)d_in[2];  // [1024][512][2][2] f32
    const float* wout = (const float*)d_in[3];  // [512][512] f32
    float* out = (float*)d_out;                 // [4][512][64][64] f32

    char* ws = (char*)d_ws;
    ushort_t* xT    = (ushort_t*)(ws);               // 16.78 MB  [b][p][c]
    ushort_t* qsb   = (ushort_t*)(ws + 16777216);    // 16.78 MB  [b][c][p]
    ushort_t* ksb   = (ushort_t*)(ws + 33554432);    //  4.19 MB  [b][h][j][d]
    ushort_t* vtb   = (ushort_t*)(ws + 37748736);    //  4.19 MB  [b][h][d][j]
    ushort_t* aob   = (ushort_t*)(ws + 41943040);    // 16.78 MB  [b][i][c]
    ushort_t* wqb   = (ushort_t*)(ws + 58720256);    //  0.52 MB
    ushort_t* wkvT  = (ushort_t*)(ws + 59244544);    //  4.19 MB  [o2][(q,c)]
    ushort_t* woutb = (ushort_t*)(ws + 63438848);    //  0.52 MB

    cvt_xT_kernel  <<<dim3(64, 8, 4), 256, 0, stream>>>(x, xT);
    cvt_kernel     <<<dim3(128),      256, 0, stream>>>(wq, wqb, 32768);
    cvt_wkvT_kernel<<<dim3(2048),     256, 0, stream>>>(wkv, wkvT);
    cvt_kernel     <<<dim3(128),      256, 0, stream>>>(wout, woutb, 32768);

    qproj_kernel  <<<dim3(32, 4, 4),  512, 0, stream>>>(xT, wqb, qsb);
    kv_kernel     <<<dim3(8, 16, 4),  512, 0, stream>>>(xT, wkvT, ksb, vtb);
    attn_kernel   <<<dim3(16, 8, 4),  256, 0, stream>>>(qsb, ksb, vtb, aob);
    outproj_kernel<<<dim3(32, 4, 4),  512, 0, stream>>>(aob, woutb, out);
}

// Round 11
// 192.288 us; speedup vs baseline: 1.2189x; 1.0367x over previous
//
#include <hip/hip_runtime.h>
#include <hip/hip_bf16.h>

typedef __bf16 bf16x8 __attribute__((ext_vector_type(8)));
typedef float f32x4 __attribute__((ext_vector_type(4)));
typedef unsigned short ushort_t;
typedef ushort_t ushort8 __attribute__((ext_vector_type(8)));
typedef unsigned uint2v __attribute__((ext_vector_type(2)));
typedef unsigned uint4v __attribute__((ext_vector_type(4)));

#define DIM 512
#define HEADS 8
#define HD 64
#define HWN 4096   // 64*64 queries per batch
#define KVN 1024   // 32*32 kv tokens per batch
#define KKV 2048   // 512*2*2 im2col K for the strided conv
#define LOG2E 1.44269504f

__device__ __forceinline__ ushort_t f2bf(float f) {
    union { float f; unsigned u; } v; v.f = f;
    unsigned r = v.u + 0x7fffu + ((v.u >> 16) & 1u);
    return (ushort_t)(r >> 16);
}

// pack two f32 -> one dword of 2 bf16 (RNE), low16 = lo
__device__ __forceinline__ unsigned cvtpk(float lo, float hi) {
    unsigned r;
    asm("v_cvt_pk_bf16_f32 %0, %1, %2" : "=v"(r) : "v"(lo), "v"(hi));
    return r;
}

__device__ __forceinline__ void pl32swap(unsigned &a, unsigned &b) {
    asm("v_permlane32_swap_b32 %0, %1" : "+v"(a), "+v"(b));
}
__device__ __forceinline__ void pl16swap(unsigned &a, unsigned &b) {
    asm("v_permlane16_swap_b32 %0, %1" : "+v"(a), "+v"(b));
}

__device__ __forceinline__ bf16x8 frag4(unsigned a, unsigned b, unsigned c, unsigned d) {
    uint4v t; t[0] = a; t[1] = b; t[2] = c; t[3] = d;
    return __builtin_bit_cast(bf16x8, t);
}

// async global->LDS, 16 B per lane; lds dest is wave-uniform base + lane*16
__device__ __forceinline__ void gload_lds16(const ushort_t* g, ushort_t* l) {
    __builtin_amdgcn_global_load_lds(
        (const __attribute__((address_space(1))) unsigned int*)(const void*)g,
        (__attribute__((address_space(3))) unsigned int*)(void*)l,
        16, 0, 0);
}

// explicit drain of outstanding global_load_lds before the barrier
__device__ __forceinline__ void drain_sync() {
    asm volatile("s_waitcnt vmcnt(0)" ::: "memory");
    __syncthreads();
}

// ---------------------------------------------------------------------------
// Kernel 0a: small f32 -> bf16 convert (wq, wout)
// ---------------------------------------------------------------------------
__global__ __launch_bounds__(256) void cvt_kernel(
        const float* __restrict__ src, ushort_t* __restrict__ dst, int n8) {
    int i = blockIdx.x * 256 + threadIdx.x;
    if (i >= n8) return;
    const float* p = &src[(size_t)i * 8];
    f32x4 v0 = *(const f32x4*)&p[0];
    f32x4 v1 = *(const f32x4*)&p[4];
    ushort8 w;
    w[0] = f2bf(v0[0]); w[1] = f2bf(v0[1]); w[2] = f2bf(v0[2]); w[3] = f2bf(v0[3]);
    w[4] = f2bf(v1[0]); w[5] = f2bf(v1[1]); w[6] = f2bf(v1[2]); w[7] = f2bf(v1[3]);
    *(ushort8*)&dst[i * 8] = w;
}

// ---------------------------------------------------------------------------
// Kernel 0b: x f32 [b][c][p] -> xT bf16 [b][p][c]   (tiled 64x64 transpose)
// ---------------------------------------------------------------------------
__global__ __launch_bounds__(256) void cvt_xT_kernel(
        const float* __restrict__ x, ushort_t* __restrict__ xT) {
    const int b  = blockIdx.z;
    const int c0 = blockIdx.y * 64;
    const int p0 = blockIdx.x * 64;
    __shared__ ushort_t tile[64 * 72];

    const int tid = threadIdx.x;
    {
        int r = tid >> 2, pc = (tid & 3) * 16;
        const float* src = &x[((size_t)b * DIM + c0 + r) * HWN + p0 + pc];
        f32x4 v0 = *(const f32x4*)&src[0];
        f32x4 v1 = *(const f32x4*)&src[4];
        f32x4 v2 = *(const f32x4*)&src[8];
        f32x4 v3 = *(const f32x4*)&src[12];
        ushort8 w0, w1;
        w0[0]=f2bf(v0[0]); w0[1]=f2bf(v0[1]); w0[2]=f2bf(v0[2]); w0[3]=f2bf(v0[3]);
        w0[4]=f2bf(v1[0]); w0[5]=f2bf(v1[1]); w0[6]=f2bf(v1[2]); w0[7]=f2bf(v1[3]);
        w1[0]=f2bf(v2[0]); w1[1]=f2bf(v2[1]); w1[2]=f2bf(v2[2]); w1[3]=f2bf(v2[3]);
        w1[4]=f2bf(v3[0]); w1[5]=f2bf(v3[1]); w1[6]=f2bf(v3[2]); w1[7]=f2bf(v3[3]);
        *(ushort8*)&tile[r * 72 + pc]     = w0;
        *(ushort8*)&tile[r * 72 + pc + 8] = w1;
    }
    __syncthreads();
    {
        int p = tid >> 2, cc = (tid & 3) * 16;
        ushort8 w0, w1;
        #pragma unroll
        for (int j = 0; j < 8; ++j) {
            w0[j] = tile[(cc + j) * 72 + p];
            w1[j] = tile[(cc + 8 + j) * 72 + p];
        }
        ushort_t* dst = &xT[((size_t)b * HWN + p0 + p) * DIM + c0 + cc];
        *(ushort8*)&dst[0] = w0;
        *(ushort8*)&dst[8] = w1;
    }
}

// ---------------------------------------------------------------------------
// Kernel 0c: wkv f32 [o2][c][di][dj] -> wkvT bf16 [o2][(di*2+dj)*512 + c]
// ---------------------------------------------------------------------------
__global__ __launch_bounds__(256) void cvt_wkvT_kernel(
        const float* __restrict__ wkv, ushort_t* __restrict__ wkvT) {
    int i = blockIdx.x * 256 + threadIdx.x;
    if (i >= 1024 * 512) return;
    int o2 = i >> 9, c = i & 511;
    f32x4 v = *(const f32x4*)&wkv[(size_t)i * 4];
    #pragma unroll
    for (int q = 0; q < 4; ++q)
        wkvT[(size_t)o2 * KKV + q * 512 + c] = f2bf(v[q]);
}

// ---------------------------------------------------------------------------
// 512-thread GEMM helper: 128x128 tile, BK=64, 8 waves (2M x 4N, each 64x32),
// XOR-swizzled LDS (rule #21).
// ---------------------------------------------------------------------------
__device__ __forceinline__ void gemm_compute_512(
        const ushort_t* __restrict__ sA, const ushort_t* __restrict__ sB,
        int wm, int wn, int l15, int quad, f32x4 (&acc)[4][2]) {
    bf16x8 a[2][4], bb[2][2];
    #pragma unroll
    for (int kk = 0; kk < 2; ++kk) {
        #pragma unroll
        for (int i = 0; i < 4; ++i) {
            int ra = wm + i * 16 + l15;
            a[kk][i] = *(const bf16x8*)&sA[ra * 64 + (((kk * 4 + quad) ^ (ra & 7)) * 8)];
        }
        #pragma unroll
        for (int j = 0; j < 2; ++j) {
            int rb = wn + j * 16 + l15;
            bb[kk][j] = *(const bf16x8*)&sB[rb * 64 + (((kk * 4 + quad) ^ (rb & 7)) * 8)];
        }
    }
    #pragma unroll
    for (int i = 0; i < 4; ++i)
        #pragma unroll
        for (int j = 0; j < 2; ++j) {
            acc[i][j] = __builtin_amdgcn_mfma_f32_16x16x32_bf16(a[0][i], bb[0][j], acc[i][j], 0, 0, 0);
            acc[i][j] = __builtin_amdgcn_mfma_f32_16x16x32_bf16(a[1][i], bb[1][j], acc[i][j], 0, 0, 0);
        }
}

// ---------------------------------------------------------------------------
// Kernel 1: Q projection, 512-thread blocks.
// Qs[b][o][p] = (0.125*log2e) * sum_c Wq[o][c]*X[c][p]
// ---------------------------------------------------------------------------
__global__ __launch_bounds__(512, 4) void qproj_kernel(
        const ushort_t* __restrict__ xT, const ushort_t* __restrict__ wqb,
        ushort_t* __restrict__ qs) {
    const int b  = blockIdx.z;
    const int m0 = blockIdx.y * 128;
    const int n0 = blockIdx.x * 128;

    __shared__ ushort_t shA[2][128 * 64];
    __shared__ ushort_t shB[2][128 * 64];

    const int tid  = threadIdx.x;
    const int wave = tid >> 6;          // 0..7
    const int lane = tid & 63;
    const int l15  = lane & 15;
    const int quad = lane >> 4;
    const int wm   = (wave >> 2) * 64;  // 2 M-waves
    const int wn   = (wave & 3) * 32;   // 4 N-waves
    const int r8   = lane >> 3;
    const int c8   = (lane & 7) ^ r8;   // inverse-swizzled source chunk

    const ushort_t* aS[2];
    const ushort_t* bS[2];
    #pragma unroll
    for (int g = 0; g < 2; ++g) {
        int row = g * 64 + wave * 8 + r8;
        aS[g] = &wqb[(size_t)(m0 + row) * DIM + c8 * 8];
        bS[g] = &xT[((size_t)b * HWN + n0 + row) * DIM + c8 * 8];
    }
    const int ldso = wave * 8 * 64;

    f32x4 zero = {0.f, 0.f, 0.f, 0.f};
    f32x4 acc[4][2];
    #pragma unroll
    for (int i = 0; i < 4; ++i)
        #pragma unroll
        for (int j = 0; j < 2; ++j) acc[i][j] = zero;

    #pragma unroll
    for (int g = 0; g < 2; ++g) {
        gload_lds16(aS[g], &shA[0][g * 4096 + ldso]);
        gload_lds16(bS[g], &shB[0][g * 4096 + ldso]);
    }
    drain_sync();

    for (int t = 0; t < 8; ++t) {
        const int cur = t & 1;
        if (t < 7) {
            const int ko = (t + 1) * 64;
            #pragma unroll
            for (int g = 0; g < 2; ++g) {
                gload_lds16(aS[g] + ko, &shA[cur ^ 1][g * 4096 + ldso]);
                gload_lds16(bS[g] + ko, &shB[cur ^ 1][g * 4096 + ldso]);
            }
        }
        gemm_compute_512(shA[cur], shB[cur], wm, wn, l15, quad, acc);
        drain_sync();
    }

    #pragma unroll
    for (int i = 0; i < 4; ++i)
        #pragma unroll
        for (int j = 0; j < 2; ++j)
            #pragma unroll
            for (int r = 0; r < 4; ++r) {
                int m = m0 + wm + i * 16 + quad * 4 + r;
                int n = n0 + wn + j * 16 + l15;
                qs[((size_t)b * DIM + m) * HWN + n] =
                    f2bf(acc[i][j][r] * (0.125f * LOG2E));
            }
}

// ---------------------------------------------------------------------------
// Kernel 2: KV conv-GEMM, 64x128 tiles, 512-thread blocks (8 waves 2Mx4N,
// each 32x32).  A = wkvT rows [64], B = im2col-gathered xT tokens [128].
// ---------------------------------------------------------------------------
__global__ __launch_bounds__(512, 4) void kv_kernel(
        const ushort_t* __restrict__ xT, const ushort_t* __restrict__ wkvT,
        ushort_t* __restrict__ ks, ushort_t* __restrict__ vt) {
    const int b  = blockIdx.z;
    const int m0 = blockIdx.y * 64;       // o2 rows
    const int j0 = blockIdx.x * 128;      // tokens

    __shared__ ushort_t shA[2][64 * 64];    // 16 KB
    __shared__ ushort_t shB[2][128 * 64];   // 32 KB

    const int tid  = threadIdx.x;
    const int wave = tid >> 6;
    const int lane = tid & 63;
    const int l15  = lane & 15;
    const int quad = lane >> 4;
    const int wm   = (wave >> 2) * 32;
    const int wn   = (wave & 3) * 32;
    const int r8   = lane >> 3;
    const int c8   = (lane & 7) ^ r8;

    const ushort_t* aS = &wkvT[(size_t)(m0 + wave * 8 + r8) * KKV + c8 * 8];
    const ushort_t* bS[2];
    #pragma unroll
    for (int g = 0; g < 2; ++g) {
        int row = g * 64 + wave * 8 + r8;
        int jr = j0 + row;
        int y = jr >> 5, x = jr & 31;
        bS[g] = &xT[((size_t)b * HWN + 128 * y + 2 * x) * DIM + c8 * 8];
    }
    const int ldso = wave * 8 * 64;

    f32x4 zero = {0.f, 0.f, 0.f, 0.f};
    f32x4 acc[2][2];
    #pragma unroll
    for (int i = 0; i < 2; ++i)
        #pragma unroll
        for (int j = 0; j < 2; ++j) acc[i][j] = zero;

    gload_lds16(aS, &shA[0][ldso]);
    #pragma unroll
    for (int g = 0; g < 2; ++g)
        gload_lds16(bS[g], &shB[0][g * 4096 + ldso]);
    drain_sync();

    for (int t = 0; t < 32; ++t) {
        const int cur = t & 1;
        if (t < 31) {
            const int tn = t + 1;
            const int qn = tn >> 3;
            const int ao = tn * 64;
            const int bo = (64 * (qn >> 1) + (qn & 1)) * DIM + (tn & 7) * 64;
            gload_lds16(aS + ao, &shA[cur ^ 1][ldso]);
            #pragma unroll
            for (int g = 0; g < 2; ++g)
                gload_lds16(bS[g] + bo, &shB[cur ^ 1][g * 4096 + ldso]);
        }
        {
            bf16x8 a[2][2], bb[2][2];
            #pragma unroll
            for (int kk = 0; kk < 2; ++kk) {
                #pragma unroll
                for (int i = 0; i < 2; ++i) {
                    int ra = wm + i * 16 + l15;
                    a[kk][i] = *(const bf16x8*)&shA[cur][ra * 64 + (((kk * 4 + quad) ^ (ra & 7)) * 8)];
                }
                #pragma unroll
                for (int j = 0; j < 2; ++j) {
                    int rb = wn + j * 16 + l15;
                    bb[kk][j] = *(const bf16x8*)&shB[cur][rb * 64 + (((kk * 4 + quad) ^ (rb & 7)) * 8)];
                }
            }
            #pragma unroll
            for (int i = 0; i < 2; ++i)
                #pragma unroll
                for (int j = 0; j < 2; ++j) {
                    acc[i][j] = __builtin_amdgcn_mfma_f32_16x16x32_bf16(a[0][i], bb[0][j], acc[i][j], 0, 0, 0);
                    acc[i][j] = __builtin_amdgcn_mfma_f32_16x16x32_bf16(a[1][i], bb[1][j], acc[i][j], 0, 0, 0);
                }
        }
        drain_sync();
    }

    if (m0 < DIM) {
        const int h = m0 >> 6;
        ushort_t* cbuf = &shB[0][0];
        #pragma unroll
        for (int i = 0; i < 2; ++i)
            #pragma unroll
            for (int j = 0; j < 2; ++j)
                #pragma unroll
                for (int r = 0; r < 4; ++r) {
                    int m = wm + i * 16 + quad * 4 + r;    // d 0..63
                    int n = wn + j * 16 + l15;             // 0..127
                    cbuf[n * 72 + m] = f2bf(acc[i][j][r]);
                }
        __syncthreads();
        {
            int n = tid >> 2, doff = (tid & 3) * 16;
            ushort8 u0 = *(const ushort8*)&cbuf[n * 72 + doff];
            ushort8 u1 = *(const ushort8*)&cbuf[n * 72 + doff + 8];
            ushort_t* dst =
                &ks[(((size_t)b * HEADS + h) * KVN + j0 + n) * HD + doff];
            *(ushort8*)&dst[0] = u0;
            *(ushort8*)&dst[8] = u1;
        }
    } else {
        const int h = (m0 - DIM) >> 6;
        #pragma unroll
        for (int i = 0; i < 2; ++i)
            #pragma unroll
            for (int j = 0; j < 2; ++j)
                #pragma unroll
                for (int r = 0; r < 4; ++r) {
                    int dd = wm + i * 16 + quad * 4 + r;   // 0..63
                    int n  = wn + j * 16 + l15;            // 0..127
                    vt[(((size_t)b * HEADS + h) * HD + dd) * KVN + j0 + n] =
                        f2bf(acc[i][j][r]);
                }
    }
}

// ---------------------------------------------------------------------------
// Kernel 3: attention — R3/R7-R10 structure + two attn-local additions:
// (1) XCD head-grouping remap: hardware XCD = linear_block_id % 8, so with
//     h = l&7, XCD c hosts exactly head c's 64 blocks -> per-XCD K/V working
//     set drops 8 MB (L2 thrash) -> 1 MB (L2-resident); chunk prefetches
//     become L2 hits hidden under compute.  Pure index permutation.
// (2) T5: s_setprio(1) around the QK and PV MFMA clusters (m191: +4-7% attn).
// ---------------------------------------------------------------------------
__global__ __launch_bounds__(256, 2) void attn_kernel(
        const ushort_t* __restrict__ qs,   // [b][c][p], pre-scaled by 0.125*log2e
        const ushort_t* __restrict__ ks,   // [b][h][j][d]
        const ushort_t* __restrict__ vt,   // [b][h][d][j]
        ushort_t* __restrict__ ao) {       // [b][i][c]
    const int l = blockIdx.x + 16 * blockIdx.y + 128 * blockIdx.z;
    const int h    = l & 7;          // XCD = l % 8 = h  -> head-per-XCD
    const int b    = l >> 7;
    const int iblk = (l >> 3) & 15;
    const int tid = threadIdx.x, wave = tid >> 6, lane = tid & 63;
    const int l15 = lane & 15, quad = lane >> 4;
    const int s7  = l15 & 7;
    const int iw = iblk * 256 + wave * 64;

    __shared__ ushort_t ldsK[2][64 * 64];
    __shared__ ushort_t ldsV[2][64 * 64];

    const ushort_t* Kh = &ks[((size_t)b * HEADS + h) * (KVN * HD)];
    const ushort_t* Vh = &vt[((size_t)b * HEADS + h) * (HD * KVN)];

    const int srow = wave * 8 + (lane >> 3);
    const int schk = (lane & 7) ^ (lane >> 3);
    const ushort_t* kp0 = Kh + srow * HD + schk * 8;
    const ushort_t* kp1 = Kh + (srow + 32) * HD + schk * 8;
    const ushort_t* vp0 = Vh + (size_t)srow * KVN + schk * 8;
    const ushort_t* vp1 = Vh + (size_t)(srow + 32) * KVN + schk * 8;

    bf16x8 bq[4][2];
    #pragma unroll
    for (int ih = 0; ih < 4; ++ih)
        #pragma unroll
        for (int kk = 0; kk < 2; ++kk) {
            ushort8 t;
            #pragma unroll
            for (int j = 0; j < 8; ++j) {
                int c = h * HD + kk * 32 + quad * 8 + j;
                int p = iw + ih * 16 + l15;
                t[j] = qs[((size_t)b * DIM + c) * HWN + p];
            }
            bq[ih][kk] = *(bf16x8*)&t;
        }

    f32x4 zero = {0.f, 0.f, 0.f, 0.f};
    f32x4 o[4][4];
    #pragma unroll
    for (int ih = 0; ih < 4; ++ih)
        #pragma unroll
        for (int nt = 0; nt < 4; ++nt) o[ih][nt] = zero;
    float ssum[4] = {0.f, 0.f, 0.f, 0.f};

    gload_lds16(kp0, &ldsK[0][wave * 512]);
    gload_lds16(kp1, &ldsK[0][wave * 512 + 2048]);
    gload_lds16(vp0, &ldsV[0][wave * 512]);
    gload_lds16(vp1, &ldsV[0][wave * 512 + 2048]);
    asm volatile("s_waitcnt vmcnt(0)" ::: "memory");
    __syncthreads();

    for (int t = 0; t < 16; ++t) {
        const int cur = t & 1;
        if (t < 15) {
            const int jn = (t + 1) * 64;
            gload_lds16(kp0 + jn * HD, &ldsK[cur ^ 1][wave * 512]);
            gload_lds16(kp1 + jn * HD, &ldsK[cur ^ 1][wave * 512 + 2048]);
            gload_lds16(vp0 + jn,      &ldsV[cur ^ 1][wave * 512]);
            gload_lds16(vp1 + jn,      &ldsV[cur ^ 1][wave * 512 + 2048]);
        }

        unsigned P2[4][4][2];
        #pragma unroll
        for (int nt = 0; nt < 4; ++nt) {
            const ushort_t* kb = &ldsK[cur][(nt * 16 + l15) * 64];
            bf16x8 bk0 = *(const bf16x8*)&kb[(quad ^ s7) * 8];
            bf16x8 bk1 = *(const bf16x8*)&kb[((quad + 4) ^ s7) * 8];
            #pragma unroll
            for (int ih = 0; ih < 4; ++ih) {
                f32x4 s = zero;
                __builtin_amdgcn_s_setprio(1);
                s = __builtin_amdgcn_mfma_f32_16x16x32_bf16(bk0, bq[ih][0], s, 0, 0, 0);
                s = __builtin_amdgcn_mfma_f32_16x16x32_bf16(bk1, bq[ih][1], s, 0, 0, 0);
                __builtin_amdgcn_s_setprio(0);
                float p0 = __builtin_amdgcn_exp2f(s[0]);
                float p1 = __builtin_amdgcn_exp2f(s[1]);
                float p2 = __builtin_amdgcn_exp2f(s[2]);
                float p3 = __builtin_amdgcn_exp2f(s[3]);
                ssum[ih] += (p0 + p1) + (p2 + p3);
                P2[ih][nt][0] = cvtpk(p0, p1);
                P2[ih][nt][1] = cvtpk(p2, p3);
            }
        }

        #pragma unroll
        for (int ih = 0; ih < 4; ++ih)
            #pragma unroll
            for (int bh = 0; bh < 2; ++bh)
                #pragma unroll
                for (int rp = 0; rp < 2; ++rp) {
                    pl32swap(P2[ih][bh * 2][rp], P2[ih][bh * 2 + 1][rp]);
                    pl16swap(P2[ih][bh * 2][rp], P2[ih][bh * 2 + 1][rp]);
                }
        bf16x8 bp[4][2];
        #pragma unroll
        for (int ih = 0; ih < 4; ++ih) {
            bp[ih][0] = frag4(P2[ih][0][0], P2[ih][0][1], P2[ih][1][0], P2[ih][1][1]);
            bp[ih][1] = frag4(P2[ih][2][0], P2[ih][2][1], P2[ih][3][0], P2[ih][3][1]);
        }

        #pragma unroll
        for (int nt = 0; nt < 4; ++nt) {
            const ushort_t* vb = &ldsV[cur][(nt * 16 + l15) * 64];
            bf16x8 bv0 = *(const bf16x8*)&vb[(quad ^ s7) * 8];
            bf16x8 bv1 = *(const bf16x8*)&vb[((quad + 4) ^ s7) * 8];
            __builtin_amdgcn_s_setprio(1);
            #pragma unroll
            for (int ih = 0; ih < 4; ++ih) {
                o[ih][nt] = __builtin_amdgcn_mfma_f32_16x16x32_bf16(bv0, bp[ih][0], o[ih][nt], 0, 0, 0);
                o[ih][nt] = __builtin_amdgcn_mfma_f32_16x16x32_bf16(bv1, bp[ih][1], o[ih][nt], 0, 0, 0);
            }
            __builtin_amdgcn_s_setprio(0);
        }

        asm volatile("s_waitcnt vmcnt(0)" ::: "memory");
        __syncthreads();
    }

    #pragma unroll
    for (int ih = 0; ih < 4; ++ih) {
        float tsum = ssum[ih];
        tsum += __shfl_xor(tsum, 16);
        tsum += __shfl_xor(tsum, 32);
        float invl = 1.0f / tsum;
        int i = iw + ih * 16 + l15;
        ushort_t* dst = &ao[((size_t)b * HWN + i) * DIM + h * HD];
        #pragma unroll
        for (int nt = 0; nt < 4; ++nt) {
            unsigned d0 = cvtpk(o[ih][nt][0] * invl, o[ih][nt][1] * invl);
            unsigned d1 = cvtpk(o[ih][nt][2] * invl, o[ih][nt][3] * invl);
            uint2v w; w[0] = d0; w[1] = d1;
            *(uint2v*)&dst[nt * 16 + quad * 4] = w;
        }
    }
}

// ---------------------------------------------------------------------------
// Kernel 4: output projection, 512-thread blocks.
// out[b][o][p] = sum_c Wout[o][c] * AO[b][p][c]   (f32 output)
// ---------------------------------------------------------------------------
__global__ __launch_bounds__(512, 4) void outproj_kernel(
        const ushort_t* __restrict__ ao, const ushort_t* __restrict__ woutb,
        float* __restrict__ out) {
    const int b  = blockIdx.z;
    const int m0 = blockIdx.y * 128;
    const int n0 = blockIdx.x * 128;

    __shared__ ushort_t shA[2][128 * 64];
    __shared__ ushort_t shB[2][128 * 64];

    const int tid  = threadIdx.x;
    const int wave = tid >> 6;
    const int lane = tid & 63;
    const int l15  = lane & 15;
    const int quad = lane >> 4;
    const int wm   = (wave >> 2) * 64;
    const int wn   = (wave & 3) * 32;
    const int r8   = lane >> 3;
    const int c8   = (lane & 7) ^ r8;

    const ushort_t* aS[2];
    const ushort_t* bS[2];
    #pragma unroll
    for (int g = 0; g < 2; ++g) {
        int row = g * 64 + wave * 8 + r8;
        aS[g] = &woutb[(size_t)(m0 + row) * DIM + c8 * 8];
        bS[g] = &ao[((size_t)b * HWN + n0 + row) * DIM + c8 * 8];
    }
    const int ldso = wave * 8 * 64;

    f32x4 zero = {0.f, 0.f, 0.f, 0.f};
    f32x4 acc[4][2];
    #pragma unroll
    for (int i = 0; i < 4; ++i)
        #pragma unroll
        for (int j = 0; j < 2; ++j) acc[i][j] = zero;

    #pragma unroll
    for (int g = 0; g < 2; ++g) {
        gload_lds16(aS[g], &shA[0][g * 4096 + ldso]);
        gload_lds16(bS[g], &shB[0][g * 4096 + ldso]);
    }
    drain_sync();

    for (int t = 0; t < 8; ++t) {
        const int cur = t & 1;
        if (t < 7) {
            const int ko = (t + 1) * 64;
            #pragma unroll
            for (int g = 0; g < 2; ++g) {
                gload_lds16(aS[g] + ko, &shA[cur ^ 1][g * 4096 + ldso]);
                gload_lds16(bS[g] + ko, &shB[cur ^ 1][g * 4096 + ldso]);
            }
        }
        gemm_compute_512(shA[cur], shB[cur], wm, wn, l15, quad, acc);
        drain_sync();
    }

    #pragma unroll
    for (int i = 0; i < 4; ++i)
        #pragma unroll
        for (int j = 0; j < 2; ++j)
            #pragma unroll
            for (int r = 0; r < 4; ++r) {
                int m = m0 + wm + i * 16 + quad * 4 + r;
                int n = n0 + wn + j * 16 + l15;
                out[((size_t)b * DIM + m) * HWN + n] = acc[i][j][r];
            }
}

// ---------------------------------------------------------------------------
extern "C" void kernel_launch(void* const* d_in, const int* in_sizes, int n_in,
                              void* d_out, int out_size, void* d_ws, size_t ws_size,
                              hipStream_t stream) {
    const float* x    = (const float*)d_in[0];  // [4][512][64][64] f32
    const float* wq   = (const float*)d_in[1];  // [512][512] f32
    const float* wkv  = (const float*)d_in[2];  // [1024][512][2][2] f32
    const float* wout = (const float*)d_in[3];  // [512][512] f32
    float* out = (float*)d_out;                 // [4][512][64][64] f32

    char* ws = (char*)d_ws;
    ushort_t* xT    = (ushort_t*)(ws);               // 16.78 MB  [b][p][c]
    ushort_t* qsb   = (ushort_t*)(ws + 16777216);    // 16.78 MB  [b][c][p]
    ushort_t* ksb   = (ushort_t*)(ws + 33554432);    //  4.19 MB  [b][h][j][d]
    ushort_t* vtb   = (ushort_t*)(ws + 37748736);    //  4.19 MB  [b][h][d][j]
    ushort_t* aob   = (ushort_t*)(ws + 41943040);    // 16.78 MB  [b][i][c]
    ushort_t* wqb   = (ushort_t*)(ws + 58720256);    //  0.52 MB
    ushort_t* wkvT  = (ushort_t*)(ws + 59244544);    //  4.19 MB  [o2][(q,c)]
    ushort_t* woutb = (ushort_t*)(ws + 63438848);    //  0.52 MB

    cvt_xT_kernel  <<<dim3(64, 8, 4), 256, 0, stream>>>(x, xT);
    cvt_kernel     <<<dim3(128),      256, 0, stream>>>(wq, wqb, 32768);
    cvt_wkvT_kernel<<<dim3(2048),     256, 0, stream>>>(wkv, wkvT);
    cvt_kernel     <<<dim3(128),      256, 0, stream>>>(wout, woutb, 32768);

    qproj_kernel  <<<dim3(32, 4, 4),  512, 0, stream>>>(xT, wqb, qsb);
    kv_kernel     <<<dim3(8, 16, 4),  512, 0, stream>>>(xT, wkvT, ksb, vtb);
    attn_kernel   <<<dim3(16, 8, 4),  256, 0, stream>>>(qsb, ksb, vtb, aob);
    outproj_kernel<<<dim3(32, 4, 4),  512, 0, stream>>>(aob, woutb, out);
}

// Round 14
// 191.962 us; speedup vs baseline: 1.2210x; 1.0017x over previous
//
#include <hip/hip_runtime.h>
#include <hip/hip_bf16.h>

typedef __bf16 bf16x8 __attribute__((ext_vector_type(8)));
typedef float f32x4 __attribute__((ext_vector_type(4)));
typedef unsigned short ushort_t;
typedef ushort_t ushort8 __attribute__((ext_vector_type(8)));
typedef unsigned uint2v __attribute__((ext_vector_type(2)));
typedef unsigned uint4v __attribute__((ext_vector_type(4)));

#define DIM 512
#define HEADS 8
#define HD 64
#define HWN 4096   // 64*64 queries per batch
#define KVN 1024   // 32*32 kv tokens per batch
#define KKV 2048   // 512*2*2 im2col K for the strided conv
#define LOG2E 1.44269504f

__device__ __forceinline__ ushort_t f2bf(float f) {
    union { float f; unsigned u; } v; v.f = f;
    unsigned r = v.u + 0x7fffu + ((v.u >> 16) & 1u);
    return (ushort_t)(r >> 16);
}

// pack two f32 -> one dword of 2 bf16 (RNE), low16 = lo
__device__ __forceinline__ unsigned cvtpk(float lo, float hi) {
    unsigned r;
    asm("v_cvt_pk_bf16_f32 %0, %1, %2" : "=v"(r) : "v"(lo), "v"(hi));
    return r;
}

__device__ __forceinline__ void pl32swap(unsigned &a, unsigned &b) {
    asm("v_permlane32_swap_b32 %0, %1" : "+v"(a), "+v"(b));
}
__device__ __forceinline__ void pl16swap(unsigned &a, unsigned &b) {
    asm("v_permlane16_swap_b32 %0, %1" : "+v"(a), "+v"(b));
}

__device__ __forceinline__ bf16x8 frag4(unsigned a, unsigned b, unsigned c, unsigned d) {
    uint4v t; t[0] = a; t[1] = b; t[2] = c; t[3] = d;
    return __builtin_bit_cast(bf16x8, t);
}

// async global->LDS, 16 B per lane; lds dest is wave-uniform base + lane*16
__device__ __forceinline__ void gload_lds16(const ushort_t* g, ushort_t* l) {
    __builtin_amdgcn_global_load_lds(
        (const __attribute__((address_space(1))) unsigned int*)(const void*)g,
        (__attribute__((address_space(3))) unsigned int*)(void*)l,
        16, 0, 0);
}

// explicit drain of outstanding global_load_lds before the barrier
__device__ __forceinline__ void drain_sync() {
    asm volatile("s_waitcnt vmcnt(0)" ::: "memory");
    __syncthreads();
}

// ---------------------------------------------------------------------------
// Kernel 0a: merged small f32 -> bf16 convert (wq then wout in one dispatch)
// ---------------------------------------------------------------------------
__global__ __launch_bounds__(256) void cvt_w2_kernel(
        const float* __restrict__ wq, const float* __restrict__ wout,
        ushort_t* __restrict__ wqb, ushort_t* __restrict__ woutb) {
    int i = blockIdx.x * 256 + threadIdx.x;        // 0..65535, each 8 floats
    const float* src;
    ushort_t* dst;
    if (i < 32768) { src = &wq[(size_t)i * 8];              dst = &wqb[(size_t)i * 8]; }
    else           { src = &wout[(size_t)(i - 32768) * 8];  dst = &woutb[(size_t)(i - 32768) * 8]; }
    f32x4 v0 = *(const f32x4*)&src[0];
    f32x4 v1 = *(const f32x4*)&src[4];
    ushort8 w;
    w[0] = f2bf(v0[0]); w[1] = f2bf(v0[1]); w[2] = f2bf(v0[2]); w[3] = f2bf(v0[3]);
    w[4] = f2bf(v1[0]); w[5] = f2bf(v1[1]); w[6] = f2bf(v1[2]); w[7] = f2bf(v1[3]);
    *(ushort8*)dst = w;
}

// ---------------------------------------------------------------------------
// Kernel 0b: x f32 [b][c][p] -> xT bf16 [b][p][c]   (tiled 64x64 transpose)
// ---------------------------------------------------------------------------
__global__ __launch_bounds__(256) void cvt_xT_kernel(
        const float* __restrict__ x, ushort_t* __restrict__ xT) {
    const int b  = blockIdx.z;
    const int c0 = blockIdx.y * 64;
    const int p0 = blockIdx.x * 64;
    __shared__ ushort_t tile[64 * 72];

    const int tid = threadIdx.x;
    {
        int r = tid >> 2, pc = (tid & 3) * 16;
        const float* src = &x[((size_t)b * DIM + c0 + r) * HWN + p0 + pc];
        f32x4 v0 = *(const f32x4*)&src[0];
        f32x4 v1 = *(const f32x4*)&src[4];
        f32x4 v2 = *(const f32x4*)&src[8];
        f32x4 v3 = *(const f32x4*)&src[12];
        ushort8 w0, w1;
        w0[0]=f2bf(v0[0]); w0[1]=f2bf(v0[1]); w0[2]=f2bf(v0[2]); w0[3]=f2bf(v0[3]);
        w0[4]=f2bf(v1[0]); w0[5]=f2bf(v1[1]); w0[6]=f2bf(v1[2]); w0[7]=f2bf(v1[3]);
        w1[0]=f2bf(v2[0]); w1[1]=f2bf(v2[1]); w1[2]=f2bf(v2[2]); w1[3]=f2bf(v2[3]);
        w1[4]=f2bf(v3[0]); w1[5]=f2bf(v3[1]); w1[6]=f2bf(v3[2]); w1[7]=f2bf(v3[3]);
        *(ushort8*)&tile[r * 72 + pc]     = w0;
        *(ushort8*)&tile[r * 72 + pc + 8] = w1;
    }
    __syncthreads();
    {
        int p = tid >> 2, cc = (tid & 3) * 16;
        ushort8 w0, w1;
        #pragma unroll
        for (int j = 0; j < 8; ++j) {
            w0[j] = tile[(cc + j) * 72 + p];
            w1[j] = tile[(cc + 8 + j) * 72 + p];
        }
        ushort_t* dst = &xT[((size_t)b * HWN + p0 + p) * DIM + c0 + cc];
        *(ushort8*)&dst[0] = w0;
        *(ushort8*)&dst[8] = w1;
    }
}

// ---------------------------------------------------------------------------
// Kernel 0c: wkv f32 [o2][c][di][dj] -> wkvT bf16 [o2][(di*2+dj)*512 + c]
// ---------------------------------------------------------------------------
__global__ __launch_bounds__(256) void cvt_wkvT_kernel(
        const float* __restrict__ wkv, ushort_t* __restrict__ wkvT) {
    int i = blockIdx.x * 256 + threadIdx.x;
    if (i >= 1024 * 512) return;
    int o2 = i >> 9, c = i & 511;
    f32x4 v = *(const f32x4*)&wkv[(size_t)i * 4];
    #pragma unroll
    for (int q = 0; q < 4; ++q)
        wkvT[(size_t)o2 * KKV + q * 512 + c] = f2bf(v[q]);
}

// ---------------------------------------------------------------------------
// 512-thread GEMM helper: 128x128 tile, BK=64, 8 waves (2M x 4N, each 64x32),
// XOR-swizzled LDS (rule #21).
// ---------------------------------------------------------------------------
__device__ __forceinline__ void gemm_compute_512(
        const ushort_t* __restrict__ sA, const ushort_t* __restrict__ sB,
        int wm, int wn, int l15, int quad, f32x4 (&acc)[4][2]) {
    bf16x8 a[2][4], bb[2][2];
    #pragma unroll
    for (int kk = 0; kk < 2; ++kk) {
        #pragma unroll
        for (int i = 0; i < 4; ++i) {
            int ra = wm + i * 16 + l15;
            a[kk][i] = *(const bf16x8*)&sA[ra * 64 + (((kk * 4 + quad) ^ (ra & 7)) * 8)];
        }
        #pragma unroll
        for (int j = 0; j < 2; ++j) {
            int rb = wn + j * 16 + l15;
            bb[kk][j] = *(const bf16x8*)&sB[rb * 64 + (((kk * 4 + quad) ^ (rb & 7)) * 8)];
        }
    }
    #pragma unroll
    for (int i = 0; i < 4; ++i)
        #pragma unroll
        for (int j = 0; j < 2; ++j) {
            acc[i][j] = __builtin_amdgcn_mfma_f32_16x16x32_bf16(a[0][i], bb[0][j], acc[i][j], 0, 0, 0);
            acc[i][j] = __builtin_amdgcn_mfma_f32_16x16x32_bf16(a[1][i], bb[1][j], acc[i][j], 0, 0, 0);
        }
}

// ---------------------------------------------------------------------------
// Kernel 1: Q projection, 512-thread blocks.
// Qs[b][o][p] = (0.125*log2e) * sum_c Wq[o][c]*X[c][p]
// ---------------------------------------------------------------------------
__global__ __launch_bounds__(512, 4) void qproj_kernel(
        const ushort_t* __restrict__ xT, const ushort_t* __restrict__ wqb,
        ushort_t* __restrict__ qs) {
    const int b  = blockIdx.z;
    const int m0 = blockIdx.y * 128;
    const int n0 = blockIdx.x * 128;

    __shared__ ushort_t shA[2][128 * 64];
    __shared__ ushort_t shB[2][128 * 64];

    const int tid  = threadIdx.x;
    const int wave = tid >> 6;          // 0..7
    const int lane = tid & 63;
    const int l15  = lane & 15;
    const int quad = lane >> 4;
    const int wm   = (wave >> 2) * 64;  // 2 M-waves
    const int wn   = (wave & 3) * 32;   // 4 N-waves
    const int r8   = lane >> 3;
    const int c8   = (lane & 7) ^ r8;   // inverse-swizzled source chunk

    const ushort_t* aS[2];
    const ushort_t* bS[2];
    #pragma unroll
    for (int g = 0; g < 2; ++g) {
        int row = g * 64 + wave * 8 + r8;
        aS[g] = &wqb[(size_t)(m0 + row) * DIM + c8 * 8];
        bS[g] = &xT[((size_t)b * HWN + n0 + row) * DIM + c8 * 8];
    }
    const int ldso = wave * 8 * 64;

    f32x4 zero = {0.f, 0.f, 0.f, 0.f};
    f32x4 acc[4][2];
    #pragma unroll
    for (int i = 0; i < 4; ++i)
        #pragma unroll
        for (int j = 0; j < 2; ++j) acc[i][j] = zero;

    #pragma unroll
    for (int g = 0; g < 2; ++g) {
        gload_lds16(aS[g], &shA[0][g * 4096 + ldso]);
        gload_lds16(bS[g], &shB[0][g * 4096 + ldso]);
    }
    drain_sync();

    for (int t = 0; t < 8; ++t) {
        const int cur = t & 1;
        if (t < 7) {
            const int ko = (t + 1) * 64;
            #pragma unroll
            for (int g = 0; g < 2; ++g) {
                gload_lds16(aS[g] + ko, &shA[cur ^ 1][g * 4096 + ldso]);
                gload_lds16(bS[g] + ko, &shB[cur ^ 1][g * 4096 + ldso]);
            }
        }
        gemm_compute_512(shA[cur], shB[cur], wm, wn, l15, quad, acc);
        drain_sync();
    }

    #pragma unroll
    for (int i = 0; i < 4; ++i)
        #pragma unroll
        for (int j = 0; j < 2; ++j)
            #pragma unroll
            for (int r = 0; r < 4; ++r) {
                int m = m0 + wm + i * 16 + quad * 4 + r;
                int n = n0 + wn + j * 16 + l15;
                qs[((size_t)b * DIM + m) * HWN + n] =
                    f2bf(acc[i][j][r] * (0.125f * LOG2E));
            }
}

// ---------------------------------------------------------------------------
// Kernel 2: KV conv-GEMM, 64x128 tiles, 512-thread blocks (8 waves 2Mx4N,
// each 32x32).  A = wkvT rows [64], B = im2col-gathered xT tokens [128].
// ---------------------------------------------------------------------------
__global__ __launch_bounds__(512, 4) void kv_kernel(
        const ushort_t* __restrict__ xT, const ushort_t* __restrict__ wkvT,
        ushort_t* __restrict__ ks, ushort_t* __restrict__ vt) {
    const int b  = blockIdx.z;
    const int m0 = blockIdx.y * 64;       // o2 rows
    const int j0 = blockIdx.x * 128;      // tokens

    __shared__ ushort_t shA[2][64 * 64];    // 16 KB
    __shared__ ushort_t shB[2][128 * 64];   // 32 KB

    const int tid  = threadIdx.x;
    const int wave = tid >> 6;
    const int lane = tid & 63;
    const int l15  = lane & 15;
    const int quad = lane >> 4;
    const int wm   = (wave >> 2) * 32;
    const int wn   = (wave & 3) * 32;
    const int r8   = lane >> 3;
    const int c8   = (lane & 7) ^ r8;

    const ushort_t* aS = &wkvT[(size_t)(m0 + wave * 8 + r8) * KKV + c8 * 8];
    const ushort_t* bS[2];
    #pragma unroll
    for (int g = 0; g < 2; ++g) {
        int row = g * 64 + wave * 8 + r8;
        int jr = j0 + row;
        int y = jr >> 5, x = jr & 31;
        bS[g] = &xT[((size_t)b * HWN + 128 * y + 2 * x) * DIM + c8 * 8];
    }
    const int ldso = wave * 8 * 64;

    f32x4 zero = {0.f, 0.f, 0.f, 0.f};
    f32x4 acc[2][2];
    #pragma unroll
    for (int i = 0; i < 2; ++i)
        #pragma unroll
        for (int j = 0; j < 2; ++j) acc[i][j] = zero;

    gload_lds16(aS, &shA[0][ldso]);
    #pragma unroll
    for (int g = 0; g < 2; ++g)
        gload_lds16(bS[g], &shB[0][g * 4096 + ldso]);
    drain_sync();

    for (int t = 0; t < 32; ++t) {
        const int cur = t & 1;
        if (t < 31) {
            const int tn = t + 1;
            const int qn = tn >> 3;
            const int ao = tn * 64;
            const int bo = (64 * (qn >> 1) + (qn & 1)) * DIM + (tn & 7) * 64;
            gload_lds16(aS + ao, &shA[cur ^ 1][ldso]);
            #pragma unroll
            for (int g = 0; g < 2; ++g)
                gload_lds16(bS[g] + bo, &shB[cur ^ 1][g * 4096 + ldso]);
        }
        {
            bf16x8 a[2][2], bb[2][2];
            #pragma unroll
            for (int kk = 0; kk < 2; ++kk) {
                #pragma unroll
                for (int i = 0; i < 2; ++i) {
                    int ra = wm + i * 16 + l15;
                    a[kk][i] = *(const bf16x8*)&shA[cur][ra * 64 + (((kk * 4 + quad) ^ (ra & 7)) * 8)];
                }
                #pragma unroll
                for (int j = 0; j < 2; ++j) {
                    int rb = wn + j * 16 + l15;
                    bb[kk][j] = *(const bf16x8*)&shB[cur][rb * 64 + (((kk * 4 + quad) ^ (rb & 7)) * 8)];
                }
            }
            #pragma unroll
            for (int i = 0; i < 2; ++i)
                #pragma unroll
                for (int j = 0; j < 2; ++j) {
                    acc[i][j] = __builtin_amdgcn_mfma_f32_16x16x32_bf16(a[0][i], bb[0][j], acc[i][j], 0, 0, 0);
                    acc[i][j] = __builtin_amdgcn_mfma_f32_16x16x32_bf16(a[1][i], bb[1][j], acc[i][j], 0, 0, 0);
                }
        }
        drain_sync();
    }

    if (m0 < DIM) {
        const int h = m0 >> 6;
        ushort_t* cbuf = &shB[0][0];
        #pragma unroll
        for (int i = 0; i < 2; ++i)
            #pragma unroll
            for (int j = 0; j < 2; ++j)
                #pragma unroll
                for (int r = 0; r < 4; ++r) {
                    int m = wm + i * 16 + quad * 4 + r;    // d 0..63
                    int n = wn + j * 16 + l15;             // 0..127
                    cbuf[n * 72 + m] = f2bf(acc[i][j][r]);
                }
        __syncthreads();
        {
            int n = tid >> 2, doff = (tid & 3) * 16;
            ushort8 u0 = *(const ushort8*)&cbuf[n * 72 + doff];
            ushort8 u1 = *(const ushort8*)&cbuf[n * 72 + doff + 8];
            ushort_t* dst =
                &ks[(((size_t)b * HEADS + h) * KVN + j0 + n) * HD + doff];
            *(ushort8*)&dst[0] = u0;
            *(ushort8*)&dst[8] = u1;
        }
    } else {
        const int h = (m0 - DIM) >> 6;
        #pragma unroll
        for (int i = 0; i < 2; ++i)
            #pragma unroll
            for (int j = 0; j < 2; ++j)
                #pragma unroll
                for (int r = 0; r < 4; ++r) {
                    int dd = wm + i * 16 + quad * 4 + r;   // 0..63
                    int n  = wn + j * 16 + l15;            // 0..127
                    vt[(((size_t)b * HEADS + h) * HD + dd) * KVN + j0 + n] =
                        f2bf(acc[i][j][r]);
                }
    }
}

// ---------------------------------------------------------------------------
// Kernel 3: attention — byte-exact R7-R10 version (4 consecutive HW passes):
// 64 queries/wave, grid (16,8,4), launch_bounds (256,2), LDS-staged K/V
// double-buffered, in-register softmax (swapped QK^T + cvt_pk + permlane).
// XCD remap + setprio experiments (R11-R13) REVERTED: remap-without-setprio
// failed deterministically twice (absmax 0.153); remap bought no time anyway
// (R11: FETCH 41->12.3 MB but attn time unchanged -> not fetch-bound).
// ---------------------------------------------------------------------------
__global__ __launch_bounds__(256, 2) void attn_kernel(
        const ushort_t* __restrict__ qs,   // [b][c][p], pre-scaled by 0.125*log2e
        const ushort_t* __restrict__ ks,   // [b][h][j][d]
        const ushort_t* __restrict__ vt,   // [b][h][d][j]
        ushort_t* __restrict__ ao) {       // [b][i][c]
    const int b = blockIdx.z, h = blockIdx.y;
    const int tid = threadIdx.x, wave = tid >> 6, lane = tid & 63;
    const int l15 = lane & 15, quad = lane >> 4;
    const int s7  = l15 & 7;
    const int iw = blockIdx.x * 256 + wave * 64;

    __shared__ ushort_t ldsK[2][64 * 64];
    __shared__ ushort_t ldsV[2][64 * 64];

    const ushort_t* Kh = &ks[((size_t)b * HEADS + h) * (KVN * HD)];
    const ushort_t* Vh = &vt[((size_t)b * HEADS + h) * (HD * KVN)];

    const int srow = wave * 8 + (lane >> 3);
    const int schk = (lane & 7) ^ (lane >> 3);
    const ushort_t* kp0 = Kh + srow * HD + schk * 8;
    const ushort_t* kp1 = Kh + (srow + 32) * HD + schk * 8;
    const ushort_t* vp0 = Vh + (size_t)srow * KVN + schk * 8;
    const ushort_t* vp1 = Vh + (size_t)(srow + 32) * KVN + schk * 8;

    bf16x8 bq[4][2];
    #pragma unroll
    for (int ih = 0; ih < 4; ++ih)
        #pragma unroll
        for (int kk = 0; kk < 2; ++kk) {
            ushort8 t;
            #pragma unroll
            for (int j = 0; j < 8; ++j) {
                int c = h * HD + kk * 32 + quad * 8 + j;
                int p = iw + ih * 16 + l15;
                t[j] = qs[((size_t)b * DIM + c) * HWN + p];
            }
            bq[ih][kk] = *(bf16x8*)&t;
        }

    f32x4 zero = {0.f, 0.f, 0.f, 0.f};
    f32x4 o[4][4];
    #pragma unroll
    for (int ih = 0; ih < 4; ++ih)
        #pragma unroll
        for (int nt = 0; nt < 4; ++nt) o[ih][nt] = zero;
    float ssum[4] = {0.f, 0.f, 0.f, 0.f};

    gload_lds16(kp0, &ldsK[0][wave * 512]);
    gload_lds16(kp1, &ldsK[0][wave * 512 + 2048]);
    gload_lds16(vp0, &ldsV[0][wave * 512]);
    gload_lds16(vp1, &ldsV[0][wave * 512 + 2048]);
    asm volatile("s_waitcnt vmcnt(0)" ::: "memory");
    __syncthreads();

    for (int t = 0; t < 16; ++t) {
        const int cur = t & 1;
        if (t < 15) {
            const int jn = (t + 1) * 64;
            gload_lds16(kp0 + jn * HD, &ldsK[cur ^ 1][wave * 512]);
            gload_lds16(kp1 + jn * HD, &ldsK[cur ^ 1][wave * 512 + 2048]);
            gload_lds16(vp0 + jn,      &ldsV[cur ^ 1][wave * 512]);
            gload_lds16(vp1 + jn,      &ldsV[cur ^ 1][wave * 512 + 2048]);
        }

        unsigned P2[4][4][2];
        #pragma unroll
        for (int nt = 0; nt < 4; ++nt) {
            const ushort_t* kb = &ldsK[cur][(nt * 16 + l15) * 64];
            bf16x8 bk0 = *(const bf16x8*)&kb[(quad ^ s7) * 8];
            bf16x8 bk1 = *(const bf16x8*)&kb[((quad + 4) ^ s7) * 8];
            #pragma unroll
            for (int ih = 0; ih < 4; ++ih) {
                f32x4 s = zero;
                s = __builtin_amdgcn_mfma_f32_16x16x32_bf16(bk0, bq[ih][0], s, 0, 0, 0);
                s = __builtin_amdgcn_mfma_f32_16x16x32_bf16(bk1, bq[ih][1], s, 0, 0, 0);
                float p0 = __builtin_amdgcn_exp2f(s[0]);
                float p1 = __builtin_amdgcn_exp2f(s[1]);
                float p2 = __builtin_amdgcn_exp2f(s[2]);
                float p3 = __builtin_amdgcn_exp2f(s[3]);
                ssum[ih] += (p0 + p1) + (p2 + p3);
                P2[ih][nt][0] = cvtpk(p0, p1);
                P2[ih][nt][1] = cvtpk(p2, p3);
            }
        }

        #pragma unroll
        for (int ih = 0; ih < 4; ++ih)
            #pragma unroll
            for (int bh = 0; bh < 2; ++bh)
                #pragma unroll
                for (int rp = 0; rp < 2; ++rp) {
                    pl32swap(P2[ih][bh * 2][rp], P2[ih][bh * 2 + 1][rp]);
                    pl16swap(P2[ih][bh * 2][rp], P2[ih][bh * 2 + 1][rp]);
                }
        bf16x8 bp[4][2];
        #pragma unroll
        for (int ih = 0; ih < 4; ++ih) {
            bp[ih][0] = frag4(P2[ih][0][0], P2[ih][0][1], P2[ih][1][0], P2[ih][1][1]);
            bp[ih][1] = frag4(P2[ih][2][0], P2[ih][2][1], P2[ih][3][0], P2[ih][3][1]);
        }

        #pragma unroll
        for (int nt = 0; nt < 4; ++nt) {
            const ushort_t* vb = &ldsV[cur][(nt * 16 + l15) * 64];
            bf16x8 bv0 = *(const bf16x8*)&vb[(quad ^ s7) * 8];
            bf16x8 bv1 = *(const bf16x8*)&vb[((quad + 4) ^ s7) * 8];
            #pragma unroll
            for (int ih = 0; ih < 4; ++ih) {
                o[ih][nt] = __builtin_amdgcn_mfma_f32_16x16x32_bf16(bv0, bp[ih][0], o[ih][nt], 0, 0, 0);
                o[ih][nt] = __builtin_amdgcn_mfma_f32_16x16x32_bf16(bv1, bp[ih][1], o[ih][nt], 0, 0, 0);
            }
        }

        asm volatile("s_waitcnt vmcnt(0)" ::: "memory");
        __syncthreads();
    }

    #pragma unroll
    for (int ih = 0; ih < 4; ++ih) {
        float tsum = ssum[ih];
        tsum += __shfl_xor(tsum, 16);
        tsum += __shfl_xor(tsum, 32);
        float invl = 1.0f / tsum;
        int i = iw + ih * 16 + l15;
        ushort_t* dst = &ao[((size_t)b * HWN + i) * DIM + h * HD];
        #pragma unroll
        for (int nt = 0; nt < 4; ++nt) {
            unsigned d0 = cvtpk(o[ih][nt][0] * invl, o[ih][nt][1] * invl);
            unsigned d1 = cvtpk(o[ih][nt][2] * invl, o[ih][nt][3] * invl);
            uint2v w; w[0] = d0; w[1] = d1;
            *(uint2v*)&dst[nt * 16 + quad * 4] = w;
        }
    }
}

// ---------------------------------------------------------------------------
// Kernel 4: output projection, 512-thread blocks.
// out[b][o][p] = sum_c Wout[o][c] * AO[b][p][c]   (f32 output)
// ---------------------------------------------------------------------------
__global__ __launch_bounds__(512, 4) void outproj_kernel(
        const ushort_t* __restrict__ ao, const ushort_t* __restrict__ woutb,
        float* __restrict__ out) {
    const int b  = blockIdx.z;
    const int m0 = blockIdx.y * 128;
    const int n0 = blockIdx.x * 128;

    __shared__ ushort_t shA[2][128 * 64];
    __shared__ ushort_t shB[2][128 * 64];

    const int tid  = threadIdx.x;
    const int wave = tid >> 6;
    const int lane = tid & 63;
    const int l15  = lane & 15;
    const int quad = lane >> 4;
    const int wm   = (wave >> 2) * 64;
    const int wn   = (wave & 3) * 32;
    const int r8   = lane >> 3;
    const int c8   = (lane & 7) ^ r8;

    const ushort_t* aS[2];
    const ushort_t* bS[2];
    #pragma unroll
    for (int g = 0; g < 2; ++g) {
        int row = g * 64 + wave * 8 + r8;
        aS[g] = &woutb[(size_t)(m0 + row) * DIM + c8 * 8];
        bS[g] = &ao[((size_t)b * HWN + n0 + row) * DIM + c8 * 8];
    }
    const int ldso = wave * 8 * 64;

    f32x4 zero = {0.f, 0.f, 0.f, 0.f};
    f32x4 acc[4][2];
    #pragma unroll
    for (int i = 0; i < 4; ++i)
        #pragma unroll
        for (int j = 0; j < 2; ++j) acc[i][j] = zero;

    #pragma unroll
    for (int g = 0; g < 2; ++g) {
        gload_lds16(aS[g], &shA[0][g * 4096 + ldso]);
        gload_lds16(bS[g], &shB[0][g * 4096 + ldso]);
    }
    drain_sync();

    for (int t = 0; t < 8; ++t) {
        const int cur = t & 1;
        if (t < 7) {
            const int ko = (t + 1) * 64;
            #pragma unroll
            for (int g = 0; g < 2; ++g) {
                gload_lds16(aS[g] + ko, &shA[cur ^ 1][g * 4096 + ldso]);
                gload_lds16(bS[g] + ko, &shB[cur ^ 1][g * 4096 + ldso]);
            }
        }
        gemm_compute_512(shA[cur], shB[cur], wm, wn, l15, quad, acc);
        drain_sync();
    }

    #pragma unroll
    for (int i = 0; i < 4; ++i)
        #pragma unroll
        for (int j = 0; j < 2; ++j)
            #pragma unroll
            for (int r = 0; r < 4; ++r) {
                int m = m0 + wm + i * 16 + quad * 4 + r;
                int n = n0 + wn + j * 16 + l15;
                out[((size_t)b * DIM + m) * HWN + n] = acc[i][j][r];
            }
}

// ---------------------------------------------------------------------------
extern "C" void kernel_launch(void* const* d_in, const int* in_sizes, int n_in,
                              void* d_out, int out_size, void* d_ws, size_t ws_size,
                              hipStream_t stream) {
    const float* x    = (const float*)d_in[0];  // [4][512][64][64] f32
    const float* wq   = (const float*)d_in[1];  // [512][512] f32
    const float* wkv  = (const float*)d_in[2];  // [1024][512][2][2] f32
    const float* wout = (const float*)d_in[3];  // [512][512] f32
    float* out = (float*)d_out;                 // [4][512][64][64] f32

    char* ws = (char*)d_ws;
    ushort_t* xT    = (ushort_t*)(ws);               // 16.78 MB  [b][p][c]
    ushort_t* qsb   = (ushort_t*)(ws + 16777216);    // 16.78 MB  [b][c][p]
    ushort_t* ksb   = (ushort_t*)(ws + 33554432);    //  4.19 MB  [b][h][j][d]
    ushort_t* vtb   = (ushort_t*)(ws + 37748736);    //  4.19 MB  [b][h][d][j]
    ushort_t* aob   = (ushort_t*)(ws + 41943040);    // 16.78 MB  [b][i][c]
    ushort_t* wqb   = (ushort_t*)(ws + 58720256);    //  0.52 MB
    ushort_t* wkvT  = (ushort_t*)(ws + 59244544);    //  4.19 MB  [o2][(q,c)]
    ushort_t* woutb = (ushort_t*)(ws + 63438848);    //  0.52 MB

    cvt_xT_kernel  <<<dim3(64, 8, 4), 256, 0, stream>>>(x, xT);
    cvt_w2_kernel  <<<dim3(256),      256, 0, stream>>>(wq, wout, wqb, woutb);
    cvt_wkvT_kernel<<<dim3(2048),     256, 0, stream>>>(wkv, wkvT);

    qproj_kernel  <<<dim3(32, 4, 4),  512, 0, stream>>>(xT, wqb, qsb);
    kv_kernel     <<<dim3(8, 16, 4),  512, 0, stream>>>(xT, wkvT, ksb, vtb);
    attn_kernel   <<<dim3(16, 8, 4),  256, 0, stream>>>(qsb, ksb, vtb, aob);
    outproj_kernel<<<dim3(32, 4, 4),  512, 0, stream>>>(aob, woutb, out);
}